// Round 1
// 7863.145 us; speedup vs baseline: 1.0757x; 1.0757x over previous
//
#include <hip/hip_runtime.h>
#include <math.h>

// Sizes fixed by setup_inputs(): H=2048, IN=128, OUT=128, T=512, STEPS=64
#define H    2048
#define IN_  128
#define OUT_ 128
#define T_   512
#define STEPS 64

// ---------------------------------------------------------------------------
// Generic tiled GEMM: C[M,N] = A[M,K] @ B[N,K]^T + bias[N]   (all row-major)
// ---------------------------------------------------------------------------
#define BM 64
#define BN 64
#define BK 16
__global__ __launch_bounds__(256) void gemm_abt(
    const float* __restrict__ A, const float* __restrict__ B,
    const float* __restrict__ bias, float* __restrict__ C,
    int M, int N, int K)
{
    __shared__ float As[BM][BK + 1];
    __shared__ float Bs[BN][BK + 1];
    int tid = threadIdx.x;
    int m0 = blockIdx.y * BM, n0 = blockIdx.x * BN;
    int ty = tid / 16, tx = tid % 16;
    float acc[4][4] = {};
    int r = tid >> 2, q = tid & 3;
    for (int k0 = 0; k0 < K; k0 += BK) {
        float4 a4 = *(const float4*)(A + (size_t)(m0 + r) * K + k0 + q * 4);
        As[r][q * 4 + 0] = a4.x; As[r][q * 4 + 1] = a4.y;
        As[r][q * 4 + 2] = a4.z; As[r][q * 4 + 3] = a4.w;
        float4 b4 = *(const float4*)(B + (size_t)(n0 + r) * K + k0 + q * 4);
        Bs[r][q * 4 + 0] = b4.x; Bs[r][q * 4 + 1] = b4.y;
        Bs[r][q * 4 + 2] = b4.z; Bs[r][q * 4 + 3] = b4.w;
        __syncthreads();
#pragma unroll
        for (int kk = 0; kk < BK; kk++) {
            float a[4], b[4];
#pragma unroll
            for (int i = 0; i < 4; i++) a[i] = As[ty * 4 + i][kk];
#pragma unroll
            for (int j = 0; j < 4; j++) b[j] = Bs[tx * 4 + j][kk];
#pragma unroll
            for (int i = 0; i < 4; i++)
#pragma unroll
                for (int j = 0; j < 4; j++) acc[i][j] += a[i] * b[j];
        }
        __syncthreads();
    }
#pragma unroll
    for (int i = 0; i < 4; i++)
#pragma unroll
        for (int j = 0; j < 4; j++)
            C[(size_t)(m0 + ty * 4 + i) * N + n0 + tx * 4 + j] =
                acc[i][j] + bias[n0 + tx * 4 + j];
}

// ---------------------------------------------------------------------------
// Fence-free grid sync (proven pattern from encoder): data moves via relaxed
// agent-scope atomics (IC-coherent, bypassing stale L1/L2). Arrival flag is
// stored by tid 0 AFTER __syncthreads() (whose implicit per-wave
// s_waitcnt vmcnt(0) drains every wave's data stores to the coherence point
// first). Waiters poll all 256 arrival flags directly (single-level: one
// fewer serialized IC round trip than the old two-level barrier). NO
// agent-scope fences anywhere (those lower to full L2 writeback/invalidate).
// ---------------------------------------------------------------------------
__device__ __forceinline__ void gsync(unsigned* __restrict__ ctrl, unsigned e)
{
    __syncthreads();  // all waves' prior global stores drained (vmcnt 0)
    if (threadIdx.x == 0) {
        __builtin_amdgcn_fence(__ATOMIC_RELEASE, "workgroup");  // compile order
        __hip_atomic_store(&ctrl[blockIdx.x], e, __ATOMIC_RELAXED,
                           __HIP_MEMORY_SCOPE_AGENT);
    }
    if (threadIdx.x < 256) {
        while (__hip_atomic_load(&ctrl[threadIdx.x], __ATOMIC_RELAXED,
                                 __HIP_MEMORY_SCOPE_AGENT) < e)
            __builtin_amdgcn_s_sleep(1);
    }
    __builtin_amdgcn_fence(__ATOMIC_ACQUIRE, "workgroup");  // compile order
    __syncthreads();
}

// ---------------------------------------------------------------------------
// Persistent encoder: 256 blocks x 512 threads, 1 block/CU.
// Block b owns hidden units j0=8b..j0+7 (24 rows of Whh register-resident).
// Barrier flattened: every block polls all 256 arrival flags directly.
// ---------------------------------------------------------------------------
__global__ __launch_bounds__(512, 1) void enc_persistent(
    const float* __restrict__ Whh, const float* __restrict__ bhh,
    const float* __restrict__ gi_all, float* __restrict__ enc_out,
    unsigned* __restrict__ ctrl)
{
    __shared__ float h_s[H];
    __shared__ float red_s[24];
    const int tid = threadIdx.x;
    const int wv = tid >> 6, ln = tid & 63;
    const int j0 = blockIdx.x * 8;
    unsigned* enc_u = (unsigned*)enc_out;

    // ---- one-time: weights -> registers (coalesced float4 loads) ----
    float4 wreg[3][8];
    float bias[3];
    int sidx[3];
#pragma unroll
    for (int i = 0; i < 3; i++) {
        int ridx = wv * 3 + i;            // 0..23
        int u = ridx & 7, g = ridx >> 3;  // gate 0=r,1=z,2=n
        int row = g * H + j0 + u;
        const float4* wr = (const float4*)(Whh + (size_t)row * H);
#pragma unroll
        for (int m = 0; m < 8; m++) wreg[i][m] = wr[ln + (m << 6)];
        bias[i] = bhh[row];
        sidx[i] = g * 8 + u;
    }

    for (int t = 0; t < T_; t++) {
        // h_{t-1} -> LDS via relaxed agent atomic dword loads (IC-coherent).
        {
            const size_t base = (size_t)(t - 1) * H;  // t=0 reads zero row
#pragma unroll
            for (int k = 0; k < 4; k++) {
                unsigned u = __hip_atomic_load(
                    &enc_u[base + tid + 512 * k], __ATOMIC_RELAXED,
                    __HIP_MEMORY_SCOPE_AGENT);
                h_s[tid + 512 * k] = __uint_as_float(u);
            }
        }
        float ir = 0.f, iz = 0.f, inn = 0.f;
        if (tid < 8) {
            const float* gi = gi_all + (size_t)t * 3 * H;
            ir  = gi[j0 + tid];
            iz  = gi[H + j0 + tid];
            inn = gi[2 * H + j0 + tid];
        }
        __syncthreads();

        float s0 = 0.f, s1 = 0.f, s2 = 0.f;
#pragma unroll
        for (int m = 0; m < 8; m++) {
            float4 h4 = ((const float4*)h_s)[ln + (m << 6)];
            s0 += wreg[0][m].x * h4.x + wreg[0][m].y * h4.y +
                  wreg[0][m].z * h4.z + wreg[0][m].w * h4.w;
            s1 += wreg[1][m].x * h4.x + wreg[1][m].y * h4.y +
                  wreg[1][m].z * h4.z + wreg[1][m].w * h4.w;
            s2 += wreg[2][m].x * h4.x + wreg[2][m].y * h4.y +
                  wreg[2][m].z * h4.z + wreg[2][m].w * h4.w;
        }
#pragma unroll
        for (int off = 32; off; off >>= 1) {
            s0 += __shfl_xor(s0, off, 64);
            s1 += __shfl_xor(s1, off, 64);
            s2 += __shfl_xor(s2, off, 64);
        }
        if (ln == 0) {
            red_s[sidx[0]] = s0 + bias[0];
            red_s[sidx[1]] = s1 + bias[1];
            red_s[sidx[2]] = s2 + bias[2];
        }
        __syncthreads();

        // h write (wave 0, lanes 0..7) via relaxed agent atomic stores,
        // then SAME WAVE: waitcnt (workgroup release) + arrival-flag store.
        if (tid < 8) {
            float hr = red_s[tid], hz = red_s[8 + tid], hn = red_s[16 + tid];
            float rg = 1.f / (1.f + expf(-(ir + hr)));
            float zg = 1.f / (1.f + expf(-(iz + hz)));
            float ng = tanhf(inn + rg * hn);
            float hv = (1.f - zg) * ng + zg * h_s[j0 + tid];
            __hip_atomic_store(&enc_u[(size_t)t * H + j0 + tid],
                               __float_as_uint(hv), __ATOMIC_RELAXED,
                               __HIP_MEMORY_SCOPE_AGENT);
        }
        if (tid == 0) {
            __builtin_amdgcn_fence(__ATOMIC_RELEASE, "workgroup");
            __hip_atomic_store(&ctrl[blockIdx.x], (unsigned)(t + 1),
                               __ATOMIC_RELAXED, __HIP_MEMORY_SCOPE_AGENT);
        }

        // ---- flat barrier: every block polls all 256 arrival flags ----
        if (tid < 256) {
            while (__hip_atomic_load(&ctrl[tid], __ATOMIC_RELAXED,
                                     __HIP_MEMORY_SCOPE_AGENT) <
                   (unsigned)(t + 1))
                __builtin_amdgcn_s_sleep(1);
        }
        __builtin_amdgcn_fence(__ATOMIC_ACQUIRE, "workgroup");
        __syncthreads();
    }
}

// ---------------------------------------------------------------------------
// Persistent decoder: 256 blocks x 512 threads, all 64 steps in one kernel.
// Block b owns hidden units j0=8b..j0+7. Per step, 5 fence-free grid syncs:
//   1: Wd     2: scores     3: din (emb|ctx)     4: h     5: logits
// dec_Whh (24 rows) register-resident like the encoder. Softmax over the 512
// scores and the 128-logit argmax/log-softmax are computed REDUNDANTLY per
// block (cheap) to avoid extra sync points. Cross-block data via relaxed
// agent atomics only.
// ---------------------------------------------------------------------------
__global__ __launch_bounds__(512, 1) void dec_persistent(
    const float* __restrict__ Wih, const float* __restrict__ Whh,
    const float* __restrict__ bih, const float* __restrict__ bhh,
    const float* __restrict__ h2oW, const float* __restrict__ h2ob,
    const float* __restrict__ WW, const float* __restrict__ Wb,
    const float* __restrict__ attnW, const float* __restrict__ attnb,
    const float* __restrict__ o2hW, const float* __restrict__ o2hb,
    const float* __restrict__ U, const float* __restrict__ enc_out,
    float* __restrict__ Wd_g, float* __restrict__ scores_g,
    float* __restrict__ logits_g, float* __restrict__ din_g,
    float* __restrict__ h_g, float* __restrict__ outs,
    float* __restrict__ attns, unsigned* __restrict__ ctrl)
{
    __shared__ float h_s[H];          // current h (8 KB)
    __shared__ float din_s[2 * H];    // din broadcast; first half doubles as Wd
    __shared__ float sc_s[T_];        // scores -> attention weights
    __shared__ float lg_s[OUT_];      // logits
    __shared__ float red8[8];
    __shared__ float red_gi[24], red_gh[24];
    __shared__ float m_sh, s_sh;
    __shared__ int am_sh;

    const int tid = threadIdx.x;
    const int wv = tid >> 6, ln = tid & 63;
    const int j0 = blockIdx.x * 8;
    unsigned* h_u   = (unsigned*)h_g;
    unsigned* wd_u  = (unsigned*)Wd_g;
    unsigned* sc_u  = (unsigned*)scores_g;
    unsigned* lg_u  = (unsigned*)logits_g;
    unsigned* din_u = (unsigned*)din_g;

    // ---- one-time: dec_Whh rows -> registers (same layout as encoder) ----
    float4 whreg[3][8];
    float bih_r[3], bhh_r[3];
    int sidx[3];
#pragma unroll
    for (int i = 0; i < 3; i++) {
        int ridx = wv * 3 + i;            // 0..23
        int u = ridx & 7, g = ridx >> 3;
        int row = g * H + j0 + u;
        const float4* wr = (const float4*)(Whh + (size_t)row * H);
#pragma unroll
        for (int m = 0; m < 8; m++) whreg[i][m] = wr[ln + (m << 6)];
        bih_r[i] = bih[row];
        bhh_r[i] = bhh[row];
        sidx[i] = g * 8 + u;
    }

    // initial h = enc_out[T-1] (plain loads: written by a previous kernel)
    ((float4*)h_s)[tid] = ((const float4*)(enc_out + (size_t)(T_ - 1) * H))[tid];
    int am = -1;  // step 0: inp = zeros -> emb = o2h_b
    __syncthreads();

    for (int s = 0; s < STEPS; s++) {
        const unsigned e0 = (unsigned)(s * 5);

        // ---- phase 1: Wd[j0+wv] = WW[j0+wv] . h + Wb ----
        {
            const float4* wr = (const float4*)(WW + (size_t)(j0 + wv) * H);
            float p = 0.f;
#pragma unroll
            for (int m = 0; m < 8; m++) {
                float4 w4 = wr[ln + (m << 6)];
                float4 h4 = ((const float4*)h_s)[ln + (m << 6)];
                p += w4.x * h4.x + w4.y * h4.y + w4.z * h4.z + w4.w * h4.w;
            }
#pragma unroll
            for (int off = 32; off; off >>= 1) p += __shfl_xor(p, off, 64);
            if (ln == 0)
                __hip_atomic_store(&wd_u[j0 + wv],
                    __float_as_uint(p + Wb[j0 + wv]),
                    __ATOMIC_RELAXED, __HIP_MEMORY_SCOPE_AGENT);
        }
        gsync(ctrl, e0 + 1);

        // ---- phase 2: scores for t0=2b (waves 0-3), t1=2b+1 (waves 4-7) ----
        {
#pragma unroll
            for (int k = 0; k < 4; k++)
                din_s[tid + 512 * k] = __uint_as_float(__hip_atomic_load(
                    &wd_u[tid + 512 * k], __ATOMIC_RELAXED,
                    __HIP_MEMORY_SCOPE_AGENT));
            __syncthreads();
            int t = 2 * blockIdx.x + (tid >> 8);
            int r = tid & 255;
            const float* Ut = U + (size_t)t * H;
            float p = 0.f;
#pragma unroll
            for (int k = 0; k < 8; k++) {
                int j = r + 256 * k;
                p += tanhf(Ut[j] + din_s[j]) * attnW[j];
            }
#pragma unroll
            for (int off = 32; off; off >>= 1) p += __shfl_xor(p, off, 64);
            if (ln == 0) red8[wv] = p;
            __syncthreads();
            if (tid == 0)
                __hip_atomic_store(&sc_u[2 * blockIdx.x],
                    __float_as_uint(red8[0] + red8[1] + red8[2] + red8[3] +
                                    attnb[0]),
                    __ATOMIC_RELAXED, __HIP_MEMORY_SCOPE_AGENT);
            if (tid == 256)
                __hip_atomic_store(&sc_u[2 * blockIdx.x + 1],
                    __float_as_uint(red8[4] + red8[5] + red8[6] + red8[7] +
                                    attnb[0]),
                    __ATOMIC_RELAXED, __HIP_MEMORY_SCOPE_AGENT);
        }
        gsync(ctrl, e0 + 2);

        // ---- phase 3: block-local softmax, ctx slice, emb slice ----
        {
            float sc = __uint_as_float(__hip_atomic_load(&sc_u[tid],
                           __ATOMIC_RELAXED, __HIP_MEMORY_SCOPE_AGENT));
            float m = sc;
#pragma unroll
            for (int off = 32; off; off >>= 1)
                m = fmaxf(m, __shfl_xor(m, off, 64));
            if (ln == 0) red8[wv] = m;
            __syncthreads();
            if (tid == 0) {
                float mm = red8[0];
                for (int i = 1; i < 8; i++) mm = fmaxf(mm, red8[i]);
                m_sh = mm;
            }
            __syncthreads();
            float ev = expf(sc - m_sh);
            float p = ev;
#pragma unroll
            for (int off = 32; off; off >>= 1) p += __shfl_xor(p, off, 64);
            __syncthreads();              // red8 (max) reads done before reuse
            if (ln == 0) red8[wv] = p;
            __syncthreads();
            if (tid == 0) {
                float ss = 0.f;
                for (int i = 0; i < 8; i++) ss += red8[i];
                s_sh = ss;
            }
            __syncthreads();
            float a = ev / s_sh;
            sc_s[tid] = a;
            if (blockIdx.x == 0) attns[(size_t)s * T_ + tid] = a;
            __syncthreads();
            // ctx[j0+wv] = sum_t aw[t] * enc_out[t][j0+wv]; lane ln: t=ln+64i
            float acc = 0.f;
#pragma unroll
            for (int i = 0; i < 8; i++) {
                int t = ln + (i << 6);
                acc += sc_s[t] * enc_out[(size_t)t * H + j0 + wv];
            }
#pragma unroll
            for (int off = 32; off; off >>= 1) acc += __shfl_xor(acc, off, 64);
            if (ln == 0)
                __hip_atomic_store(&din_u[H + j0 + wv], __float_as_uint(acc),
                    __ATOMIC_RELAXED, __HIP_MEMORY_SCOPE_AGENT);
            if (tid < 8) {  // emb slice: one-hot(am) @ o2h_W.T + o2h_b
                float evb = o2hb[j0 + tid];
                if (am >= 0) evb += o2hW[(size_t)(j0 + tid) * OUT_ + am];
                __hip_atomic_store(&din_u[j0 + tid], __float_as_uint(evb),
                    __ATOMIC_RELAXED, __HIP_MEMORY_SCOPE_AGENT);
            }
        }
        gsync(ctrl, e0 + 3);

        // ---- phase 4: decoder GRU (gi streams Wih from IC; gh from regs) --
        {
#pragma unroll
            for (int k = 0; k < 8; k++)
                din_s[tid + 512 * k] = __uint_as_float(__hip_atomic_load(
                    &din_u[tid + 512 * k], __ATOMIC_RELAXED,
                    __HIP_MEMORY_SCOPE_AGENT));
            __syncthreads();
#pragma unroll
            for (int i = 0; i < 3; i++) {
                int ridx = wv * 3 + i;
                int u = ridx & 7, g = ridx >> 3;
                int row = g * H + j0 + u;
                const float4* wr = (const float4*)(Wih + (size_t)row * (2 * H));
                float gi = 0.f;
#pragma unroll
                for (int k = 0; k < 16; k++) {
                    float4 w4 = wr[ln + (k << 6)];
                    float4 v4 = ((const float4*)din_s)[ln + (k << 6)];
                    gi += w4.x * v4.x + w4.y * v4.y + w4.z * v4.z + w4.w * v4.w;
                }
                float gh = 0.f;
#pragma unroll
                for (int m = 0; m < 8; m++) {
                    float4 h4 = ((const float4*)h_s)[ln + (m << 6)];
                    float4 w4 = whreg[i][m];
                    gh += w4.x * h4.x + w4.y * h4.y + w4.z * h4.z + w4.w * h4.w;
                }
#pragma unroll
                for (int off = 32; off; off >>= 1) {
                    gi += __shfl_xor(gi, off, 64);
                    gh += __shfl_xor(gh, off, 64);
                }
                if (ln == 0) {
                    red_gi[sidx[i]] = gi + bih_r[i];
                    red_gh[sidx[i]] = gh + bhh_r[i];
                }
            }
            __syncthreads();
            if (tid < 8) {
                float ir = red_gi[tid], iz = red_gi[8 + tid],
                      inn = red_gi[16 + tid];
                float hr = red_gh[tid], hz = red_gh[8 + tid],
                      hn = red_gh[16 + tid];
                float rg = 1.f / (1.f + expf(-(ir + hr)));
                float zg = 1.f / (1.f + expf(-(iz + hz)));
                float ng = tanhf(inn + rg * hn);
                float hv = (1.f - zg) * ng + zg * h_s[j0 + tid];
                __hip_atomic_store(&h_u[j0 + tid], __float_as_uint(hv),
                    __ATOMIC_RELAXED, __HIP_MEMORY_SCOPE_AGENT);
            }
        }
        gsync(ctrl, e0 + 4);

        // ---- phase 5: reload h (doubles as next step's h), logits ----
        {
#pragma unroll
            for (int k = 0; k < 4; k++)
                h_s[tid + 512 * k] = __uint_as_float(__hip_atomic_load(
                    &h_u[tid + 512 * k], __ATOMIC_RELAXED,
                    __HIP_MEMORY_SCOPE_AGENT));
            __syncthreads();
            float p = 0.f;
            if (blockIdx.x < OUT_) {  // blocks 0..127: logit row = blockIdx.x
                float4 w4 =
                    ((const float4*)(h2oW + (size_t)blockIdx.x * H))[tid];
                float4 h4 = ((const float4*)h_s)[tid];
                p = w4.x * h4.x + w4.y * h4.y + w4.z * h4.z + w4.w * h4.w;
            }
#pragma unroll
            for (int off = 32; off; off >>= 1) p += __shfl_xor(p, off, 64);
            if (ln == 0) red8[wv] = p;
            __syncthreads();
            if (blockIdx.x < OUT_ && tid == 0) {
                float ss = red8[0] + red8[1] + red8[2] + red8[3] +
                           red8[4] + red8[5] + red8[6] + red8[7];
                __hip_atomic_store(&lg_u[blockIdx.x],
                    __float_as_uint(ss + h2ob[blockIdx.x]),
                    __ATOMIC_RELAXED, __HIP_MEMORY_SCOPE_AGENT);
            }
        }
        gsync(ctrl, e0 + 5);

        // ---- block-local argmax + log-softmax (block 0 writes outs) ----
        {
            if (tid < OUT_)
                lg_s[tid] = __uint_as_float(__hip_atomic_load(&lg_u[tid],
                    __ATOMIC_RELAXED, __HIP_MEMORY_SCOPE_AGENT));
            __syncthreads();
            if (tid == 0) {
                float mx = lg_s[0]; int amx = 0;
                for (int i = 1; i < OUT_; i++)
                    if (lg_s[i] > mx) { mx = lg_s[i]; amx = i; }
                float ss = 0.f;
                for (int i = 0; i < OUT_; i++) ss += expf(lg_s[i] - mx);
                m_sh = mx; s_sh = logf(ss); am_sh = amx;
            }
            __syncthreads();
            am = am_sh;
            if (blockIdx.x == 0 && tid < OUT_)
                outs[(size_t)s * OUT_ + tid] = (lg_s[tid] - m_sh) - s_sh;
            __syncthreads();
        }
    }
}

extern "C" void kernel_launch(void* const* d_in, const int* in_sizes, int n_in,
                              void* d_out, int out_size, void* d_ws, size_t ws_size,
                              hipStream_t stream)
{
    const float* x     = (const float*)d_in[0];
    const float* eWih  = (const float*)d_in[1];
    const float* eWhh  = (const float*)d_in[2];
    const float* ebih  = (const float*)d_in[3];
    const float* ebhh  = (const float*)d_in[4];
    const float* dWih  = (const float*)d_in[5];
    const float* dWhh  = (const float*)d_in[6];
    const float* dbih  = (const float*)d_in[7];
    const float* dbhh  = (const float*)d_in[8];
    const float* h2oW  = (const float*)d_in[9];
    const float* h2ob  = (const float*)d_in[10];
    const float* UW    = (const float*)d_in[11];
    const float* Ub    = (const float*)d_in[12];
    const float* WW    = (const float*)d_in[13];
    const float* Wb    = (const float*)d_in[14];
    const float* attnW = (const float*)d_in[15];
    const float* attnb = (const float*)d_in[16];
    const float* o2hW  = (const float*)d_in[17];
    const float* o2hb  = (const float*)d_in[18];

    float* ws      = (float*)d_ws;
    unsigned* ctrl = (unsigned*)ws;                    // [0..255] enc flags, [256..511] dec flags
    float* zrow    = ws + 512;                         // 2048 zeros (h_0)
    float* enc_out = zrow + H;                         // 512*2048
    float* gi_all  = enc_out + (size_t)T_ * H;         // 512*6144
    float* U       = gi_all + (size_t)T_ * 3 * H;      // 512*2048
    float* Wd      = U + (size_t)T_ * H;               // 2048
    float* scores  = Wd + H;                           // 512
    float* logits  = scores + T_;                      // 512 (>=128 used)
    float* din     = logits + T_;                      // 4096
    float* hd      = din + 2 * H;                      // 2048 (h buffer)

    float* outs  = (float*)d_out;                      // 64*128
    float* attns = outs + STEPS * OUT_;                // 64*512

    // zero barrier flags + h0 row (d_ws is poisoned 0xAA before every call)
    hipMemsetAsync(d_ws, 0, (512 + H) * sizeof(float), stream);

    // ---- encoder ----
    gemm_abt<<<dim3(3 * H / BN, T_ / BM), 256, 0, stream>>>(
        x, eWih, ebih, gi_all, T_, 3 * H, IN_);
    enc_persistent<<<256, 512, 0, stream>>>(eWhh, ebhh, gi_all, enc_out, ctrl);

    gemm_abt<<<dim3(H / BN, T_ / BM), 256, 0, stream>>>(
        enc_out, UW, Ub, U, T_, H, H);

    // ---- decoder: single persistent kernel for all 64 steps ----
    dec_persistent<<<256, 512, 0, stream>>>(
        dWih, dWhh, dbih, dbhh, h2oW, h2ob, WW, Wb, attnW, attnb,
        o2hW, o2hb, U, enc_out,
        Wd, scores, logits, din, hd,
        outs, attns, ctrl + 256);
}

// Round 2
// 7179.288 us; speedup vs baseline: 1.1782x; 1.0953x over previous
//
#include <hip/hip_runtime.h>
#include <math.h>

// Sizes fixed by setup_inputs(): H=2048, IN=128, OUT=128, T=512, STEPS=64
#define H    2048
#define IN_  128
#define OUT_ 128
#define T_   512
#define STEPS 64

// ---------------------------------------------------------------------------
// Generic tiled GEMM: C[M,N] = A[M,K(lda)] @ B[N,K]^T + bias[N]  (row-major)
// bias may be nullptr (treated as 0).
// ---------------------------------------------------------------------------
#define BM 64
#define BN 64
#define BK 16
__global__ __launch_bounds__(256) void gemm_abt(
    const float* __restrict__ A, const float* __restrict__ B,
    const float* __restrict__ bias, float* __restrict__ C,
    int M, int N, int K, int lda)
{
    __shared__ float As[BM][BK + 1];
    __shared__ float Bs[BN][BK + 1];
    int tid = threadIdx.x;
    int m0 = blockIdx.y * BM, n0 = blockIdx.x * BN;
    int ty = tid / 16, tx = tid % 16;
    float acc[4][4] = {};
    int r = tid >> 2, q = tid & 3;
    for (int k0 = 0; k0 < K; k0 += BK) {
        float4 a4 = *(const float4*)(A + (size_t)(m0 + r) * lda + k0 + q * 4);
        As[r][q * 4 + 0] = a4.x; As[r][q * 4 + 1] = a4.y;
        As[r][q * 4 + 2] = a4.z; As[r][q * 4 + 3] = a4.w;
        float4 b4 = *(const float4*)(B + (size_t)(n0 + r) * K + k0 + q * 4);
        Bs[r][q * 4 + 0] = b4.x; Bs[r][q * 4 + 1] = b4.y;
        Bs[r][q * 4 + 2] = b4.z; Bs[r][q * 4 + 3] = b4.w;
        __syncthreads();
#pragma unroll
        for (int kk = 0; kk < BK; kk++) {
            float a[4], b[4];
#pragma unroll
            for (int i = 0; i < 4; i++) a[i] = As[ty * 4 + i][kk];
#pragma unroll
            for (int j = 0; j < 4; j++) b[j] = Bs[tx * 4 + j][kk];
#pragma unroll
            for (int i = 0; i < 4; i++)
#pragma unroll
                for (int j = 0; j < 4; j++) acc[i][j] += a[i] * b[j];
        }
        __syncthreads();
    }
#pragma unroll
    for (int j = 0; j < 4; j++) {
        float bv = bias ? bias[n0 + tx * 4 + j] : 0.f;
#pragma unroll
        for (int i = 0; i < 4; i++)
            C[(size_t)(m0 + ty * 4 + i) * N + n0 + tx * 4 + j] = acc[i][j] + bv;
    }
}

// E[c][j] = o2hW[j][c] + o2hb[j]   (128 x 2048) — the 128 possible emb vectors
__global__ __launch_bounds__(256) void ebuild_kernel(
    const float* __restrict__ o2hW, const float* __restrict__ o2hb,
    float* __restrict__ E)
{
    int j = blockIdx.x * 256 + threadIdx.x;  // 0..2047
    int c = blockIdx.y;                      // 0..127
    E[(size_t)c * H + j] = o2hW[(size_t)j * OUT_ + c] + o2hb[j];
}

// p0[row] = Wih[row, 0:2048] . o2hb     (row stride 4096) — emb for am = -1
__global__ __launch_bounds__(512) void p0_kernel(
    const float* __restrict__ Wih, const float* __restrict__ o2hb,
    float* __restrict__ p0)
{
    __shared__ float b_s[H];
    int tid = threadIdx.x;
    ((float4*)b_s)[tid] = ((const float4*)o2hb)[tid];
    __syncthreads();
    int wv = tid >> 6, ln = tid & 63;
    int row = blockIdx.x * 8 + wv;  // grid 768 -> rows 0..6143
    const float4* wr = (const float4*)(Wih + (size_t)row * (2 * H));
    float s = 0.f;
#pragma unroll
    for (int m = 0; m < 8; m++) {
        float4 w = wr[ln + (m << 6)];
        float4 b = ((const float4*)b_s)[ln + (m << 6)];
        s += w.x * b.x + w.y * b.y + w.z * b.z + w.w * b.w;
    }
#pragma unroll
    for (int off = 32; off; off >>= 1) s += __shfl_xor(s, off, 64);
    if (ln == 0) p0[row] = s;
}

// enc_T[j][t] = enc_out[t][j]   (2048 x 512) for coalesced ctx reduction
__global__ __launch_bounds__(256) void transpose_kernel(
    const float* __restrict__ in, float* __restrict__ out)
{
    __shared__ float tile[32][33];
    int tx = threadIdx.x & 31, ty = threadIdx.x >> 5;  // 8 rows of 32
    int t0 = blockIdx.y * 32, j0 = blockIdx.x * 32;
#pragma unroll
    for (int i = 0; i < 32; i += 8)
        tile[ty + i][tx] = in[(size_t)(t0 + ty + i) * H + j0 + tx];
    __syncthreads();
#pragma unroll
    for (int i = 0; i < 32; i += 8)
        out[(size_t)(j0 + ty + i) * T_ + t0 + tx] = tile[tx][ty + i];
}

// ---------------------------------------------------------------------------
// Fence-free grid sync (proven): data via relaxed agent-scope atomics
// (IC-coherent). Arrival flag stored by tid 0 after __syncthreads() (implicit
// per-wave vmcnt drain). Every block polls all 256 flags. No agent fences.
// ---------------------------------------------------------------------------
__device__ __forceinline__ void gsync(unsigned* __restrict__ ctrl, unsigned e)
{
    __syncthreads();
    if (threadIdx.x == 0) {
        __builtin_amdgcn_fence(__ATOMIC_RELEASE, "workgroup");
        __hip_atomic_store(&ctrl[blockIdx.x], e, __ATOMIC_RELAXED,
                           __HIP_MEMORY_SCOPE_AGENT);
    }
    if (threadIdx.x < 256) {
        while (__hip_atomic_load(&ctrl[threadIdx.x], __ATOMIC_RELAXED,
                                 __HIP_MEMORY_SCOPE_AGENT) < e)
            __builtin_amdgcn_s_sleep(1);
    }
    __builtin_amdgcn_fence(__ATOMIC_ACQUIRE, "workgroup");
    __syncthreads();
}

// ---------------------------------------------------------------------------
// Persistent encoder: 256 blocks x 512 threads, 1 block/CU.
// Block b owns hidden units j0=8b..j0+7 (24 rows of Whh register-resident).
// ---------------------------------------------------------------------------
__global__ __launch_bounds__(512, 1) void enc_persistent(
    const float* __restrict__ Whh, const float* __restrict__ bhh,
    const float* __restrict__ gi_all, float* __restrict__ enc_out,
    unsigned* __restrict__ ctrl)
{
    __shared__ float h_s[H];
    __shared__ float red_s[24];
    const int tid = threadIdx.x;
    const int wv = tid >> 6, ln = tid & 63;
    const int j0 = blockIdx.x * 8;
    unsigned* enc_u = (unsigned*)enc_out;

    float4 wreg[3][8];
    float bias[3];
    int sidx[3];
#pragma unroll
    for (int i = 0; i < 3; i++) {
        int ridx = wv * 3 + i;
        int u = ridx & 7, g = ridx >> 3;
        int row = g * H + j0 + u;
        const float4* wr = (const float4*)(Whh + (size_t)row * H);
#pragma unroll
        for (int m = 0; m < 8; m++) wreg[i][m] = wr[ln + (m << 6)];
        bias[i] = bhh[row];
        sidx[i] = g * 8 + u;
    }

    for (int t = 0; t < T_; t++) {
        {
            const size_t base = (size_t)(t - 1) * H;  // t=0 reads zero row
#pragma unroll
            for (int k = 0; k < 4; k++) {
                unsigned u = __hip_atomic_load(
                    &enc_u[base + tid + 512 * k], __ATOMIC_RELAXED,
                    __HIP_MEMORY_SCOPE_AGENT);
                h_s[tid + 512 * k] = __uint_as_float(u);
            }
        }
        float ir = 0.f, iz = 0.f, inn = 0.f;
        if (tid < 8) {
            const float* gi = gi_all + (size_t)t * 3 * H;
            ir  = gi[j0 + tid];
            iz  = gi[H + j0 + tid];
            inn = gi[2 * H + j0 + tid];
        }
        __syncthreads();

        float s0 = 0.f, s1 = 0.f, s2 = 0.f;
#pragma unroll
        for (int m = 0; m < 8; m++) {
            float4 h4 = ((const float4*)h_s)[ln + (m << 6)];
            s0 += wreg[0][m].x * h4.x + wreg[0][m].y * h4.y +
                  wreg[0][m].z * h4.z + wreg[0][m].w * h4.w;
            s1 += wreg[1][m].x * h4.x + wreg[1][m].y * h4.y +
                  wreg[1][m].z * h4.z + wreg[1][m].w * h4.w;
            s2 += wreg[2][m].x * h4.x + wreg[2][m].y * h4.y +
                  wreg[2][m].z * h4.z + wreg[2][m].w * h4.w;
        }
#pragma unroll
        for (int off = 32; off; off >>= 1) {
            s0 += __shfl_xor(s0, off, 64);
            s1 += __shfl_xor(s1, off, 64);
            s2 += __shfl_xor(s2, off, 64);
        }
        if (ln == 0) {
            red_s[sidx[0]] = s0 + bias[0];
            red_s[sidx[1]] = s1 + bias[1];
            red_s[sidx[2]] = s2 + bias[2];
        }
        __syncthreads();

        if (tid < 8) {
            float hr = red_s[tid], hz = red_s[8 + tid], hn = red_s[16 + tid];
            float rg = 1.f / (1.f + expf(-(ir + hr)));
            float zg = 1.f / (1.f + expf(-(iz + hz)));
            float ng = tanhf(inn + rg * hn);
            float hv = (1.f - zg) * ng + zg * h_s[j0 + tid];
            __hip_atomic_store(&enc_u[(size_t)t * H + j0 + tid],
                               __float_as_uint(hv), __ATOMIC_RELAXED,
                               __HIP_MEMORY_SCOPE_AGENT);
        }
        if (tid == 0) {
            __builtin_amdgcn_fence(__ATOMIC_RELEASE, "workgroup");
            __hip_atomic_store(&ctrl[blockIdx.x], (unsigned)(t + 1),
                               __ATOMIC_RELAXED, __HIP_MEMORY_SCOPE_AGENT);
        }
        if (tid < 256) {
            while (__hip_atomic_load(&ctrl[tid], __ATOMIC_RELAXED,
                                     __HIP_MEMORY_SCOPE_AGENT) <
                   (unsigned)(t + 1))
                __builtin_amdgcn_s_sleep(1);
        }
        __builtin_amdgcn_fence(__ATOMIC_ACQUIRE, "workgroup");
        __syncthreads();
    }
}

// ---------------------------------------------------------------------------
// Persistent decoder: 256 blocks x 512 threads, all 64 steps, 4 syncs/step:
//   A: scores          B: softmax + ctx        C: GRU -> h
//   D: logits (blocks 0..127) || next-step Wd (blocks 128..255)
// gi left-half comes from precomputed G[:,am] (or p0 for am=-1); only
// Wih_right (48 MB) streams per step. dec_Whh register-resident.
// ---------------------------------------------------------------------------
__global__ __launch_bounds__(512, 1) void dec_persistent(
    const float* __restrict__ Wih, const float* __restrict__ Whh,
    const float* __restrict__ bih, const float* __restrict__ bhh,
    const float* __restrict__ h2oW, const float* __restrict__ h2ob,
    const float* __restrict__ WW, const float* __restrict__ Wb,
    const float* __restrict__ attnW, const float* __restrict__ attnb,
    const float* __restrict__ G, const float* __restrict__ p0,
    const float* __restrict__ U, const float* __restrict__ enc_out,
    const float* __restrict__ enc_T,
    float* __restrict__ Wd_g, float* __restrict__ scores_g,
    float* __restrict__ logits_g, float* __restrict__ ctx_g,
    float* __restrict__ h_g, float* __restrict__ outs,
    float* __restrict__ attns, unsigned* __restrict__ ctrl)
{
    __shared__ __align__(16) float h_s[H];
    __shared__ __align__(16) float wd_s[H];
    __shared__ __align__(16) float ctx_s[H];
    __shared__ __align__(16) float sc_s[T_];
    __shared__ float lg_s[OUT_];
    __shared__ float red8[8];
    __shared__ float red_gi[24], red_gh[24];
    __shared__ float m_sh, s_sh;
    __shared__ int am_sh;

    const int tid = threadIdx.x;
    const int wv = tid >> 6, ln = tid & 63;
    const int j0 = blockIdx.x * 8;
    unsigned* h_u   = (unsigned*)h_g;
    unsigned* wd_u  = (unsigned*)Wd_g;
    unsigned* sc_u  = (unsigned*)scores_g;
    unsigned* lg_u  = (unsigned*)logits_g;
    unsigned* ctx_u = (unsigned*)ctx_g;

    // ---- one-time: dec_Whh rows -> registers ----
    float4 whreg[3][8];
    float bih_r[3], bhh_r[3];
    int sidx[3], rowr[3];
#pragma unroll
    for (int i = 0; i < 3; i++) {
        int ridx = wv * 3 + i;
        int u = ridx & 7, g = ridx >> 3;
        int row = g * H + j0 + u;
        const float4* wr = (const float4*)(Whh + (size_t)row * H);
#pragma unroll
        for (int m = 0; m < 8; m++) whreg[i][m] = wr[ln + (m << 6)];
        bih_r[i] = bih[row];
        bhh_r[i] = bhh[row];
        sidx[i] = g * 8 + u;
        rowr[i] = row;
    }

    // initial h = enc_out[T-1]
    ((float4*)h_s)[tid] = ((const float4*)(enc_out + (size_t)(T_ - 1) * H))[tid];
    int am = -1;
    __syncthreads();

    // ---- prologue: Wd_0 = WW @ h_T + Wb (8 rows/block, 1 per wave) ----
    {
        const float4* wr = (const float4*)(WW + (size_t)(j0 + wv) * H);
        float p = 0.f;
#pragma unroll
        for (int m = 0; m < 8; m++) {
            float4 w4 = wr[ln + (m << 6)];
            float4 h4 = ((const float4*)h_s)[ln + (m << 6)];
            p += w4.x * h4.x + w4.y * h4.y + w4.z * h4.z + w4.w * h4.w;
        }
#pragma unroll
        for (int off = 32; off; off >>= 1) p += __shfl_xor(p, off, 64);
        if (ln == 0)
            __hip_atomic_store(&wd_u[j0 + wv], __float_as_uint(p + Wb[j0 + wv]),
                __ATOMIC_RELAXED, __HIP_MEMORY_SCOPE_AGENT);
    }
    gsync(ctrl, 1u);

    for (int s = 0; s < STEPS; s++) {
        const unsigned e0 = 2u + (unsigned)(s * 4);

        // ---- phase A: scores t0=2b (waves 0-3), t1=2b+1 (waves 4-7) ----
        {
#pragma unroll
            for (int k = 0; k < 4; k++)
                wd_s[tid + 512 * k] = __uint_as_float(__hip_atomic_load(
                    &wd_u[tid + 512 * k], __ATOMIC_RELAXED,
                    __HIP_MEMORY_SCOPE_AGENT));
            __syncthreads();
            int t = 2 * blockIdx.x + (tid >> 8);
            int r = tid & 255;
            const float* Ut = U + (size_t)t * H;
            float p = 0.f;
#pragma unroll
            for (int k = 0; k < 8; k++) {
                int j = r + 256 * k;
                p += tanhf(Ut[j] + wd_s[j]) * attnW[j];
            }
#pragma unroll
            for (int off = 32; off; off >>= 1) p += __shfl_xor(p, off, 64);
            if (ln == 0) red8[wv] = p;
            __syncthreads();
            if (tid == 0)
                __hip_atomic_store(&sc_u[2 * blockIdx.x],
                    __float_as_uint(red8[0] + red8[1] + red8[2] + red8[3] +
                                    attnb[0]),
                    __ATOMIC_RELAXED, __HIP_MEMORY_SCOPE_AGENT);
            if (tid == 256)
                __hip_atomic_store(&sc_u[2 * blockIdx.x + 1],
                    __float_as_uint(red8[4] + red8[5] + red8[6] + red8[7] +
                                    attnb[0]),
                    __ATOMIC_RELAXED, __HIP_MEMORY_SCOPE_AGENT);
        }
        gsync(ctrl, e0);

        // ---- phase B: block-local softmax + coalesced ctx slice ----
        {
            float sc = __uint_as_float(__hip_atomic_load(&sc_u[tid],
                           __ATOMIC_RELAXED, __HIP_MEMORY_SCOPE_AGENT));
            float m = sc;
#pragma unroll
            for (int off = 32; off; off >>= 1)
                m = fmaxf(m, __shfl_xor(m, off, 64));
            if (ln == 0) red8[wv] = m;
            __syncthreads();
            if (tid == 0) {
                float mm = red8[0];
                for (int i = 1; i < 8; i++) mm = fmaxf(mm, red8[i]);
                m_sh = mm;
            }
            __syncthreads();
            float ev = expf(sc - m_sh);
            float p = ev;
#pragma unroll
            for (int off = 32; off; off >>= 1) p += __shfl_xor(p, off, 64);
            __syncthreads();
            if (ln == 0) red8[wv] = p;
            __syncthreads();
            if (tid == 0) {
                float ss = 0.f;
                for (int i = 0; i < 8; i++) ss += red8[i];
                s_sh = ss;
            }
            __syncthreads();
            float a = ev / s_sh;
            sc_s[tid] = a;
            if (blockIdx.x == 0) attns[(size_t)s * T_ + tid] = a;
            __syncthreads();
            // ctx[j0+wv] = aw . enc_T[j0+wv, :]  (coalesced float4 row read)
            const float4* er = (const float4*)(enc_T + (size_t)(j0 + wv) * T_);
            const float4* av = (const float4*)sc_s;
            float acc = 0.f;
#pragma unroll
            for (int i = 0; i < 2; i++) {
                float4 e4 = er[ln + (i << 6)];
                float4 a4 = av[ln + (i << 6)];
                acc += e4.x * a4.x + e4.y * a4.y + e4.z * a4.z + e4.w * a4.w;
            }
#pragma unroll
            for (int off = 32; off; off >>= 1) acc += __shfl_xor(acc, off, 64);
            if (ln == 0)
                __hip_atomic_store(&ctx_u[j0 + wv], __float_as_uint(acc),
                    __ATOMIC_RELAXED, __HIP_MEMORY_SCOPE_AGENT);
        }
        gsync(ctrl, e0 + 1);

        // ---- phase C: GRU. gi = G[:,am] + Wih_right @ ctx; gh from regs --
        {
#pragma unroll
            for (int k = 0; k < 4; k++)
                ctx_s[tid + 512 * k] = __uint_as_float(__hip_atomic_load(
                    &ctx_u[tid + 512 * k], __ATOMIC_RELAXED,
                    __HIP_MEMORY_SCOPE_AGENT));
            __syncthreads();
#pragma unroll
            for (int i = 0; i < 3; i++) {
                int row = rowr[i];
                float gil = (am >= 0) ? G[(size_t)row * OUT_ + am] : p0[row];
                const float4* wr =
                    (const float4*)(Wih + (size_t)row * (2 * H) + H);
                float gi = 0.f;
#pragma unroll
                for (int m = 0; m < 8; m++) {
                    float4 w4 = wr[ln + (m << 6)];
                    float4 v4 = ((const float4*)ctx_s)[ln + (m << 6)];
                    gi += w4.x * v4.x + w4.y * v4.y + w4.z * v4.z + w4.w * v4.w;
                }
                float gh = 0.f;
#pragma unroll
                for (int m = 0; m < 8; m++) {
                    float4 h4 = ((const float4*)h_s)[ln + (m << 6)];
                    float4 w4 = whreg[i][m];
                    gh += w4.x * h4.x + w4.y * h4.y + w4.z * h4.z + w4.w * h4.w;
                }
#pragma unroll
                for (int off = 32; off; off >>= 1) {
                    gi += __shfl_xor(gi, off, 64);
                    gh += __shfl_xor(gh, off, 64);
                }
                if (ln == 0) {
                    red_gi[sidx[i]] = gi + gil + bih_r[i];
                    red_gh[sidx[i]] = gh + bhh_r[i];
                }
            }
            __syncthreads();
            if (tid < 8) {
                float ir = red_gi[tid], iz = red_gi[8 + tid],
                      inn = red_gi[16 + tid];
                float hr = red_gh[tid], hz = red_gh[8 + tid],
                      hn = red_gh[16 + tid];
                float rg = 1.f / (1.f + expf(-(ir + hr)));
                float zg = 1.f / (1.f + expf(-(iz + hz)));
                float ng = tanhf(inn + rg * hn);
                float hv = (1.f - zg) * ng + zg * h_s[j0 + tid];
                __hip_atomic_store(&h_u[j0 + tid], __float_as_uint(hv),
                    __ATOMIC_RELAXED, __HIP_MEMORY_SCOPE_AGENT);
            }
        }
        gsync(ctrl, e0 + 2);

        // ---- phase D: reload h; logits (blocks<128) || next Wd (>=128) ----
        {
#pragma unroll
            for (int k = 0; k < 4; k++)
                h_s[tid + 512 * k] = __uint_as_float(__hip_atomic_load(
                    &h_u[tid + 512 * k], __ATOMIC_RELAXED,
                    __HIP_MEMORY_SCOPE_AGENT));
            __syncthreads();
            if (blockIdx.x < OUT_) {
                float4 w4 =
                    ((const float4*)(h2oW + (size_t)blockIdx.x * H))[tid];
                float4 h4 = ((const float4*)h_s)[tid];
                float p = w4.x * h4.x + w4.y * h4.y + w4.z * h4.z + w4.w * h4.w;
#pragma unroll
                for (int off = 32; off; off >>= 1) p += __shfl_xor(p, off, 64);
                if (ln == 0) red8[wv] = p;
                __syncthreads();
                if (tid == 0) {
                    float ss = red8[0] + red8[1] + red8[2] + red8[3] +
                               red8[4] + red8[5] + red8[6] + red8[7];
                    __hip_atomic_store(&lg_u[blockIdx.x],
                        __float_as_uint(ss + h2ob[blockIdx.x]),
                        __ATOMIC_RELAXED, __HIP_MEMORY_SCOPE_AGENT);
                }
            } else {
                int r0 = (blockIdx.x - OUT_) * 16 + wv * 2;
#pragma unroll
                for (int rr = 0; rr < 2; rr++) {
                    int row = r0 + rr;
                    const float4* wr = (const float4*)(WW + (size_t)row * H);
                    float p = 0.f;
#pragma unroll
                    for (int m = 0; m < 8; m++) {
                        float4 w4 = wr[ln + (m << 6)];
                        float4 h4 = ((const float4*)h_s)[ln + (m << 6)];
                        p += w4.x * h4.x + w4.y * h4.y + w4.z * h4.z +
                             w4.w * h4.w;
                    }
#pragma unroll
                    for (int off = 32; off; off >>= 1)
                        p += __shfl_xor(p, off, 64);
                    if (ln == 0)
                        __hip_atomic_store(&wd_u[row],
                            __float_as_uint(p + Wb[row]),
                            __ATOMIC_RELAXED, __HIP_MEMORY_SCOPE_AGENT);
                }
                __syncthreads();  // match logits-path barrier
            }
        }
        gsync(ctrl, e0 + 3);

        // ---- block-local argmax + log-softmax (block 0 writes outs) ----
        {
            if (tid < OUT_)
                lg_s[tid] = __uint_as_float(__hip_atomic_load(&lg_u[tid],
                    __ATOMIC_RELAXED, __HIP_MEMORY_SCOPE_AGENT));
            __syncthreads();
            if (tid == 0) {
                float mx = lg_s[0]; int amx = 0;
                for (int i = 1; i < OUT_; i++)
                    if (lg_s[i] > mx) { mx = lg_s[i]; amx = i; }
                float ss = 0.f;
                for (int i = 0; i < OUT_; i++) ss += expf(lg_s[i] - mx);
                m_sh = mx; s_sh = logf(ss); am_sh = amx;
            }
            __syncthreads();
            am = am_sh;
            if (blockIdx.x == 0 && tid < OUT_)
                outs[(size_t)s * OUT_ + tid] = (lg_s[tid] - m_sh) - s_sh;
            __syncthreads();
        }
    }
}

extern "C" void kernel_launch(void* const* d_in, const int* in_sizes, int n_in,
                              void* d_out, int out_size, void* d_ws, size_t ws_size,
                              hipStream_t stream)
{
    const float* x     = (const float*)d_in[0];
    const float* eWih  = (const float*)d_in[1];
    const float* eWhh  = (const float*)d_in[2];
    const float* ebih  = (const float*)d_in[3];
    const float* ebhh  = (const float*)d_in[4];
    const float* dWih  = (const float*)d_in[5];
    const float* dWhh  = (const float*)d_in[6];
    const float* dbih  = (const float*)d_in[7];
    const float* dbhh  = (const float*)d_in[8];
    const float* h2oW  = (const float*)d_in[9];
    const float* h2ob  = (const float*)d_in[10];
    const float* UW    = (const float*)d_in[11];
    const float* Ub    = (const float*)d_in[12];
    const float* WW    = (const float*)d_in[13];
    const float* Wb    = (const float*)d_in[14];
    const float* attnW = (const float*)d_in[15];
    const float* attnb = (const float*)d_in[16];
    const float* o2hW  = (const float*)d_in[17];
    const float* o2hb  = (const float*)d_in[18];

    float* ws      = (float*)d_ws;
    unsigned* ctrl = (unsigned*)ws;                    // [0..255] enc, [256..511] dec
    float* zrow    = ws + 512;                         // 2048 zeros (h_0)
    float* enc_out = zrow + H;                         // 512*2048
    float* gi_all  = enc_out + (size_t)T_ * H;         // 512*6144
    float* U       = gi_all + (size_t)T_ * 3 * H;      // 512*2048
    float* enc_T   = U + (size_t)T_ * H;               // 2048*512
    float* E       = enc_T + (size_t)H * T_;           // 128*2048
    float* G       = E + (size_t)OUT_ * H;             // 6144*128
    float* p0      = G + (size_t)3 * H * OUT_;         // 6144
    float* Wd      = p0 + 3 * H;                       // 2048
    float* scores  = Wd + H;                           // 512
    float* logits  = scores + T_;                      // 128
    float* ctx     = logits + OUT_;                    // 2048
    float* hd      = ctx + H;                          // 2048

    float* outs  = (float*)d_out;                      // 64*128
    float* attns = outs + STEPS * OUT_;                // 64*512

    // zero barrier flags + h0 row (d_ws is poisoned before every call)
    hipMemsetAsync(d_ws, 0, (512 + H) * sizeof(float), stream);

    // ---- encoder input gemm ----
    gemm_abt<<<dim3(3 * H / BN, T_ / BM), 256, 0, stream>>>(
        x, eWih, ebih, gi_all, T_, 3 * H, IN_, IN_);

    // ---- decoder precompute (independent of encoder) ----
    ebuild_kernel<<<dim3(H / 256, OUT_), 256, 0, stream>>>(o2hW, o2hb, E);
    gemm_abt<<<dim3(OUT_ / BN, 3 * H / BM), 256, 0, stream>>>(
        dWih, E, nullptr, G, 3 * H, OUT_, H, 2 * H);
    p0_kernel<<<3 * H / 8, 512, 0, stream>>>(dWih, o2hb, p0);

    // ---- encoder recurrence ----
    enc_persistent<<<256, 512, 0, stream>>>(eWhh, ebhh, gi_all, enc_out, ctrl);

    gemm_abt<<<dim3(H / BN, T_ / BM), 256, 0, stream>>>(
        enc_out, UW, Ub, U, T_, H, H, H);
    transpose_kernel<<<dim3(H / 32, T_ / 32), 256, 0, stream>>>(enc_out, enc_T);

    // ---- decoder: single persistent kernel ----
    dec_persistent<<<256, 512, 0, stream>>>(
        dWih, dWhh, dbih, dbhh, h2oW, h2ob, WW, Wb, attnW, attnb,
        G, p0, U, enc_out, enc_T,
        Wd, scores, logits, ctx, hd,
        outs, attns, ctrl + 256);
}

// Round 3
// 5408.786 us; speedup vs baseline: 1.5638x; 1.3273x over previous
//
#include <hip/hip_runtime.h>
#include <math.h>

// Sizes fixed by setup_inputs(): H=2048, IN=128, OUT=128, T=512, STEPS=64
#define H    2048
#define IN_  128
#define OUT_ 128
#define T_   512
#define STEPS 64

// ---------------------------------------------------------------------------
// Generic tiled GEMM: C[M,N] = A[M,K(lda)] @ B[N,K]^T + bias[N]  (row-major)
// ---------------------------------------------------------------------------
#define BM 64
#define BN 64
#define BK 16
__global__ __launch_bounds__(256) void gemm_abt(
    const float* __restrict__ A, const float* __restrict__ B,
    const float* __restrict__ bias, float* __restrict__ C,
    int M, int N, int K, int lda)
{
    __shared__ float As[BM][BK + 1];
    __shared__ float Bs[BN][BK + 1];
    int tid = threadIdx.x;
    int m0 = blockIdx.y * BM, n0 = blockIdx.x * BN;
    int ty = tid / 16, tx = tid % 16;
    float acc[4][4] = {};
    int r = tid >> 2, q = tid & 3;
    for (int k0 = 0; k0 < K; k0 += BK) {
        float4 a4 = *(const float4*)(A + (size_t)(m0 + r) * lda + k0 + q * 4);
        As[r][q * 4 + 0] = a4.x; As[r][q * 4 + 1] = a4.y;
        As[r][q * 4 + 2] = a4.z; As[r][q * 4 + 3] = a4.w;
        float4 b4 = *(const float4*)(B + (size_t)(n0 + r) * K + k0 + q * 4);
        Bs[r][q * 4 + 0] = b4.x; Bs[r][q * 4 + 1] = b4.y;
        Bs[r][q * 4 + 2] = b4.z; Bs[r][q * 4 + 3] = b4.w;
        __syncthreads();
#pragma unroll
        for (int kk = 0; kk < BK; kk++) {
            float a[4], b[4];
#pragma unroll
            for (int i = 0; i < 4; i++) a[i] = As[ty * 4 + i][kk];
#pragma unroll
            for (int j = 0; j < 4; j++) b[j] = Bs[tx * 4 + j][kk];
#pragma unroll
            for (int i = 0; i < 4; i++)
#pragma unroll
                for (int j = 0; j < 4; j++) acc[i][j] += a[i] * b[j];
        }
        __syncthreads();
    }
#pragma unroll
    for (int j = 0; j < 4; j++) {
        float bv = bias ? bias[n0 + tx * 4 + j] : 0.f;
#pragma unroll
        for (int i = 0; i < 4; i++)
            C[(size_t)(m0 + ty * 4 + i) * N + n0 + tx * 4 + j] = acc[i][j] + bv;
    }
}

// E[c][j] = o2hW[j][c] + o2hb[j]   (128 x 2048) — the 128 possible emb vectors
__global__ __launch_bounds__(256) void ebuild_kernel(
    const float* __restrict__ o2hW, const float* __restrict__ o2hb,
    float* __restrict__ E)
{
    int j = blockIdx.x * 256 + threadIdx.x;
    int c = blockIdx.y;
    E[(size_t)c * H + j] = o2hW[(size_t)j * OUT_ + c] + o2hb[j];
}

// p0[row] = Wih[row, 0:2048] . o2hb     (row stride 4096) — emb for am = -1
__global__ __launch_bounds__(512) void p0_kernel(
    const float* __restrict__ Wih, const float* __restrict__ o2hb,
    float* __restrict__ p0)
{
    __shared__ float b_s[H];
    int tid = threadIdx.x;
    ((float4*)b_s)[tid] = ((const float4*)o2hb)[tid];
    __syncthreads();
    int wv = tid >> 6, ln = tid & 63;
    int row = blockIdx.x * 8 + wv;
    const float4* wr = (const float4*)(Wih + (size_t)row * (2 * H));
    float s = 0.f;
#pragma unroll
    for (int m = 0; m < 8; m++) {
        float4 w = wr[ln + (m << 6)];
        float4 b = ((const float4*)b_s)[ln + (m << 6)];
        s += w.x * b.x + w.y * b.y + w.z * b.z + w.w * b.w;
    }
#pragma unroll
    for (int off = 32; off; off >>= 1) s += __shfl_xor(s, off, 64);
    if (ln == 0) p0[row] = s;
}

// ---------------------------------------------------------------------------
// Fence-free grid sync (proven): data via relaxed agent-scope atomics
// (IC-coherent). Arrival flag stored by tid 0 after __syncthreads() (implicit
// per-wave vmcnt drain). Every block polls all 256 flags. No agent fences.
// ---------------------------------------------------------------------------
__device__ __forceinline__ void gsync(unsigned* __restrict__ ctrl, unsigned e)
{
    __syncthreads();
    if (threadIdx.x == 0) {
        __builtin_amdgcn_fence(__ATOMIC_RELEASE, "workgroup");
        __hip_atomic_store(&ctrl[blockIdx.x], e, __ATOMIC_RELAXED,
                           __HIP_MEMORY_SCOPE_AGENT);
    }
    if (threadIdx.x < 256) {
        while (__hip_atomic_load(&ctrl[threadIdx.x], __ATOMIC_RELAXED,
                                 __HIP_MEMORY_SCOPE_AGENT) < e)
            __builtin_amdgcn_s_sleep(1);
    }
    __builtin_amdgcn_fence(__ATOMIC_ACQUIRE, "workgroup");
    __syncthreads();
}

// ---------------------------------------------------------------------------
// Persistent encoder: 256 blocks x 512 threads, 1 block/CU.
// Block b owns hidden units j0=8b..j0+7 (24 rows of enc_Whh AND 24 rows of
// dec_Wih_right register-resident, ~224 VGPR).
// NEW: in the barrier-wait slack of each step, compute one column of
//   M = dec_Wih_right @ enc_out^T   (6144 x 512)
// using the h_{t-1} already in LDS — a free 12.9-GFLOP GEMM that lets the
// decoder replace its Wih_right@ctx streaming with M @ aw.
// ---------------------------------------------------------------------------
__global__ __launch_bounds__(512, 2) void enc_persistent(
    const float* __restrict__ Whh, const float* __restrict__ bhh,
    const float* __restrict__ gi_all, const float* __restrict__ dWih,
    float* __restrict__ enc_out, float* __restrict__ M_ws,
    unsigned* __restrict__ ctrl)
{
    __shared__ float h_s[H];
    __shared__ float red_s[24];
    const int tid = threadIdx.x;
    const int wv = tid >> 6, ln = tid & 63;
    const int j0 = blockIdx.x * 8;
    unsigned* enc_u = (unsigned*)enc_out;

    float4 wreg[3][8];   // enc_Whh rows
    float4 dreg[3][8];   // dec_Wih right-half rows (for M)
    float bias[3];
    int sidx[3], drow[3];
#pragma unroll
    for (int i = 0; i < 3; i++) {
        int ridx = wv * 3 + i;
        int u = ridx & 7, g = ridx >> 3;
        int row = g * H + j0 + u;
        const float4* wr = (const float4*)(Whh + (size_t)row * H);
        const float4* dr = (const float4*)(dWih + (size_t)row * (2 * H) + H);
#pragma unroll
        for (int m = 0; m < 8; m++) {
            wreg[i][m] = wr[ln + (m << 6)];
            dreg[i][m] = dr[ln + (m << 6)];
        }
        bias[i] = bhh[row];
        sidx[i] = g * 8 + u;
        drow[i] = row;
    }

    for (int t = 0; t < T_; t++) {
        {
            const size_t base = (size_t)(t - 1) * H;  // t=0 reads zero row
#pragma unroll
            for (int k = 0; k < 4; k++) {
                unsigned u = __hip_atomic_load(
                    &enc_u[base + tid + 512 * k], __ATOMIC_RELAXED,
                    __HIP_MEMORY_SCOPE_AGENT);
                h_s[tid + 512 * k] = __uint_as_float(u);
            }
        }
        float ir = 0.f, iz = 0.f, inn = 0.f;
        if (tid < 8) {
            const float* gi = gi_all + (size_t)t * 3 * H;
            ir  = gi[j0 + tid];
            iz  = gi[H + j0 + tid];
            inn = gi[2 * H + j0 + tid];
        }
        __syncthreads();

        float s0 = 0.f, s1 = 0.f, s2 = 0.f;
#pragma unroll
        for (int m = 0; m < 8; m++) {
            float4 h4 = ((const float4*)h_s)[ln + (m << 6)];
            s0 += wreg[0][m].x * h4.x + wreg[0][m].y * h4.y +
                  wreg[0][m].z * h4.z + wreg[0][m].w * h4.w;
            s1 += wreg[1][m].x * h4.x + wreg[1][m].y * h4.y +
                  wreg[1][m].z * h4.z + wreg[1][m].w * h4.w;
            s2 += wreg[2][m].x * h4.x + wreg[2][m].y * h4.y +
                  wreg[2][m].z * h4.z + wreg[2][m].w * h4.w;
        }
#pragma unroll
        for (int off = 32; off; off >>= 1) {
            s0 += __shfl_xor(s0, off, 64);
            s1 += __shfl_xor(s1, off, 64);
            s2 += __shfl_xor(s2, off, 64);
        }
        if (ln == 0) {
            red_s[sidx[0]] = s0 + bias[0];
            red_s[sidx[1]] = s1 + bias[1];
            red_s[sidx[2]] = s2 + bias[2];
        }
        __syncthreads();

        if (tid < 8) {
            float hr = red_s[tid], hz = red_s[8 + tid], hn = red_s[16 + tid];
            float rg = 1.f / (1.f + expf(-(ir + hr)));
            float zg = 1.f / (1.f + expf(-(iz + hz)));
            float ng = tanhf(inn + rg * hn);
            float hv = (1.f - zg) * ng + zg * h_s[j0 + tid];
            __hip_atomic_store(&enc_u[(size_t)t * H + j0 + tid],
                               __float_as_uint(hv), __ATOMIC_RELAXED,
                               __HIP_MEMORY_SCOPE_AGENT);
        }
        if (tid == 0) {
            __builtin_amdgcn_fence(__ATOMIC_RELEASE, "workgroup");
            __hip_atomic_store(&ctrl[blockIdx.x], (unsigned)(t + 1),
                               __ATOMIC_RELAXED, __HIP_MEMORY_SCOPE_AGENT);
        }

        // ---- overlapped (flag already out): M[:,t-1] = dWih_r @ h_{t-1} ----
        {
            float m0 = 0.f, m1 = 0.f, m2 = 0.f;
#pragma unroll
            for (int m = 0; m < 8; m++) {
                float4 h4 = ((const float4*)h_s)[ln + (m << 6)];
                m0 += dreg[0][m].x * h4.x + dreg[0][m].y * h4.y +
                      dreg[0][m].z * h4.z + dreg[0][m].w * h4.w;
                m1 += dreg[1][m].x * h4.x + dreg[1][m].y * h4.y +
                      dreg[1][m].z * h4.z + dreg[1][m].w * h4.w;
                m2 += dreg[2][m].x * h4.x + dreg[2][m].y * h4.y +
                      dreg[2][m].z * h4.z + dreg[2][m].w * h4.w;
            }
#pragma unroll
            for (int off = 32; off; off >>= 1) {
                m0 += __shfl_xor(m0, off, 64);
                m1 += __shfl_xor(m1, off, 64);
                m2 += __shfl_xor(m2, off, 64);
            }
            if (ln == 0 && t > 0) {
                M_ws[(size_t)drow[0] * T_ + (t - 1)] = m0;
                M_ws[(size_t)drow[1] * T_ + (t - 1)] = m1;
                M_ws[(size_t)drow[2] * T_ + (t - 1)] = m2;
            }
        }

        if (tid < 256) {
            while (__hip_atomic_load(&ctrl[tid], __ATOMIC_RELAXED,
                                     __HIP_MEMORY_SCOPE_AGENT) <
                   (unsigned)(t + 1))
                __builtin_amdgcn_s_sleep(1);
        }
        __builtin_amdgcn_fence(__ATOMIC_ACQUIRE, "workgroup");
        __syncthreads();
    }

    // ---- epilogue: final column M[:,T-1] from h_T = enc_out[T-1] ----
    {
#pragma unroll
        for (int k = 0; k < 4; k++) {
            unsigned u = __hip_atomic_load(
                &enc_u[(size_t)(T_ - 1) * H + tid + 512 * k],
                __ATOMIC_RELAXED, __HIP_MEMORY_SCOPE_AGENT);
            h_s[tid + 512 * k] = __uint_as_float(u);
        }
        __syncthreads();
        float m0 = 0.f, m1 = 0.f, m2 = 0.f;
#pragma unroll
        for (int m = 0; m < 8; m++) {
            float4 h4 = ((const float4*)h_s)[ln + (m << 6)];
            m0 += dreg[0][m].x * h4.x + dreg[0][m].y * h4.y +
                  dreg[0][m].z * h4.z + dreg[0][m].w * h4.w;
            m1 += dreg[1][m].x * h4.x + dreg[1][m].y * h4.y +
                  dreg[1][m].z * h4.z + dreg[1][m].w * h4.w;
            m2 += dreg[2][m].x * h4.x + dreg[2][m].y * h4.y +
                  dreg[2][m].z * h4.z + dreg[2][m].w * h4.w;
        }
#pragma unroll
        for (int off = 32; off; off >>= 1) {
            m0 += __shfl_xor(m0, off, 64);
            m1 += __shfl_xor(m1, off, 64);
            m2 += __shfl_xor(m2, off, 64);
        }
        if (ln == 0) {
            M_ws[(size_t)drow[0] * T_ + (T_ - 1)] = m0;
            M_ws[(size_t)drow[1] * T_ + (T_ - 1)] = m1;
            M_ws[(size_t)drow[2] * T_ + (T_ - 1)] = m2;
        }
    }
}

// ---------------------------------------------------------------------------
// Persistent decoder: 256 blocks x 512 threads, all 64 steps, 3 syncs/step:
//   A: scores      B: softmax + FULL GRU (gi_right = M@aw, no ctx!)
//   C: logits (blocks 0..127) || next-step Wd (blocks 128..255)
// No weight streaming: Whh in registers, M-slab (24x512) + everything else
// in LDS. gi left-half from precomputed G[:,am] / p0.
// ---------------------------------------------------------------------------
__global__ __launch_bounds__(512, 1) void dec_persistent(
    const float* __restrict__ Whh,
    const float* __restrict__ bih, const float* __restrict__ bhh,
    const float* __restrict__ h2oW, const float* __restrict__ h2ob,
    const float* __restrict__ WW, const float* __restrict__ Wb,
    const float* __restrict__ attnW, const float* __restrict__ attnb,
    const float* __restrict__ G, const float* __restrict__ p0,
    const float* __restrict__ U, const float* __restrict__ enc_out,
    const float* __restrict__ M_ws,
    float* __restrict__ Wd_g, float* __restrict__ scores_g,
    float* __restrict__ logits_g, float* __restrict__ h_g,
    float* __restrict__ outs, float* __restrict__ attns,
    unsigned* __restrict__ ctrl)
{
    __shared__ __align__(16) float h_s[H];
    __shared__ __align__(16) float wd_s[H];
    __shared__ __align__(16) float sc_s[T_];
    __shared__ __align__(16) float M_s[24][T_];   // 49152 B
    __shared__ float lg_s[OUT_];
    __shared__ float red8[8];
    __shared__ float red_gi[24], red_gh[24];
    __shared__ float m_sh, s_sh;
    __shared__ int am_sh;

    const int tid = threadIdx.x;
    const int wv = tid >> 6, ln = tid & 63;
    const int j0 = blockIdx.x * 8;
    unsigned* h_u  = (unsigned*)h_g;
    unsigned* wd_u = (unsigned*)Wd_g;
    unsigned* sc_u = (unsigned*)scores_g;
    unsigned* lg_u = (unsigned*)logits_g;

    // ---- one-time: dec_Whh rows -> registers; M rows -> LDS ----
    float4 whreg[3][8];
    float bih_r[3], bhh_r[3];
    int sidx[3], rowr[3];
#pragma unroll
    for (int i = 0; i < 3; i++) {
        int ridx = wv * 3 + i;
        int u = ridx & 7, g = ridx >> 3;
        int row = g * H + j0 + u;
        const float4* wr = (const float4*)(Whh + (size_t)row * H);
#pragma unroll
        for (int m = 0; m < 8; m++) whreg[i][m] = wr[ln + (m << 6)];
        bih_r[i] = bih[row];
        bhh_r[i] = bhh[row];
        sidx[i] = g * 8 + u;
        rowr[i] = row;
#pragma unroll
        for (int k = 0; k < 8; k++)
            M_s[ridx][ln + (k << 6)] = M_ws[(size_t)row * T_ + ln + (k << 6)];
    }

    // initial h = enc_out[T-1]
    ((float4*)h_s)[tid] = ((const float4*)(enc_out + (size_t)(T_ - 1) * H))[tid];
    int am = -1;
    __syncthreads();

    // ---- prologue: Wd_0 = WW @ h_T + Wb (1 row per wave) ----
    {
        const float4* wr = (const float4*)(WW + (size_t)(j0 + wv) * H);
        float p = 0.f;
#pragma unroll
        for (int m = 0; m < 8; m++) {
            float4 w4 = wr[ln + (m << 6)];
            float4 h4 = ((const float4*)h_s)[ln + (m << 6)];
            p += w4.x * h4.x + w4.y * h4.y + w4.z * h4.z + w4.w * h4.w;
        }
#pragma unroll
        for (int off = 32; off; off >>= 1) p += __shfl_xor(p, off, 64);
        if (ln == 0)
            __hip_atomic_store(&wd_u[j0 + wv], __float_as_uint(p + Wb[j0 + wv]),
                __ATOMIC_RELAXED, __HIP_MEMORY_SCOPE_AGENT);
    }
    gsync(ctrl, 1u);

    for (int s = 0; s < STEPS; s++) {
        const unsigned e0 = 2u + (unsigned)(s * 3);

        // ---- phase A: scores t0=2b (waves 0-3), t1=2b+1 (waves 4-7) ----
        {
#pragma unroll
            for (int k = 0; k < 4; k++)
                wd_s[tid + 512 * k] = __uint_as_float(__hip_atomic_load(
                    &wd_u[tid + 512 * k], __ATOMIC_RELAXED,
                    __HIP_MEMORY_SCOPE_AGENT));
            __syncthreads();
            int t = 2 * blockIdx.x + (tid >> 8);
            int r = tid & 255;
            const float* Ut = U + (size_t)t * H;
            float p = 0.f;
#pragma unroll
            for (int k = 0; k < 8; k++) {
                int j = r + 256 * k;
                p += tanhf(Ut[j] + wd_s[j]) * attnW[j];
            }
#pragma unroll
            for (int off = 32; off; off >>= 1) p += __shfl_xor(p, off, 64);
            if (ln == 0) red8[wv] = p;
            __syncthreads();
            if (tid == 0)
                __hip_atomic_store(&sc_u[2 * blockIdx.x],
                    __float_as_uint(red8[0] + red8[1] + red8[2] + red8[3] +
                                    attnb[0]),
                    __ATOMIC_RELAXED, __HIP_MEMORY_SCOPE_AGENT);
            if (tid == 256)
                __hip_atomic_store(&sc_u[2 * blockIdx.x + 1],
                    __float_as_uint(red8[4] + red8[5] + red8[6] + red8[7] +
                                    attnb[0]),
                    __ATOMIC_RELAXED, __HIP_MEMORY_SCOPE_AGENT);
        }
        gsync(ctrl, e0);

        // ---- phase B: block-local softmax + full GRU via M@aw ----
        {
            float sc = __uint_as_float(__hip_atomic_load(&sc_u[tid],
                           __ATOMIC_RELAXED, __HIP_MEMORY_SCOPE_AGENT));
            float m = sc;
#pragma unroll
            for (int off = 32; off; off >>= 1)
                m = fmaxf(m, __shfl_xor(m, off, 64));
            if (ln == 0) red8[wv] = m;
            __syncthreads();
            if (tid == 0) {
                float mm = red8[0];
                for (int i = 1; i < 8; i++) mm = fmaxf(mm, red8[i]);
                m_sh = mm;
            }
            __syncthreads();
            float ev = expf(sc - m_sh);
            float p = ev;
#pragma unroll
            for (int off = 32; off; off >>= 1) p += __shfl_xor(p, off, 64);
            __syncthreads();
            if (ln == 0) red8[wv] = p;
            __syncthreads();
            if (tid == 0) {
                float ss = 0.f;
                for (int i = 0; i < 8; i++) ss += red8[i];
                s_sh = ss;
            }
            __syncthreads();
            float a = ev / s_sh;
            sc_s[tid] = a;
            if (blockIdx.x == 0) attns[(size_t)s * T_ + tid] = a;
            __syncthreads();

            // GRU: gi = G[:,am] + M@aw + bih ; gh = whreg@h + bhh
#pragma unroll
            for (int i = 0; i < 3; i++) {
                int row = rowr[i];
                float gil = (am >= 0) ? G[(size_t)row * OUT_ + am] : p0[row];
                const float* Mr = &M_s[wv * 3 + i][0];
                float gi = 0.f;
#pragma unroll
                for (int k = 0; k < 8; k++)
                    gi += Mr[ln + (k << 6)] * sc_s[ln + (k << 6)];
                float gh = 0.f;
#pragma unroll
                for (int m2 = 0; m2 < 8; m2++) {
                    float4 h4 = ((const float4*)h_s)[ln + (m2 << 6)];
                    float4 w4 = whreg[i][m2];
                    gh += w4.x * h4.x + w4.y * h4.y + w4.z * h4.z + w4.w * h4.w;
                }
#pragma unroll
                for (int off = 32; off; off >>= 1) {
                    gi += __shfl_xor(gi, off, 64);
                    gh += __shfl_xor(gh, off, 64);
                }
                if (ln == 0) {
                    red_gi[sidx[i]] = gi + gil + bih_r[i];
                    red_gh[sidx[i]] = gh + bhh_r[i];
                }
            }
            __syncthreads();
            if (tid < 8) {
                float ir = red_gi[tid], iz = red_gi[8 + tid],
                      inn = red_gi[16 + tid];
                float hr = red_gh[tid], hz = red_gh[8 + tid],
                      hn = red_gh[16 + tid];
                float rg = 1.f / (1.f + expf(-(ir + hr)));
                float zg = 1.f / (1.f + expf(-(iz + hz)));
                float ng = tanhf(inn + rg * hn);
                float hv = (1.f - zg) * ng + zg * h_s[j0 + tid];
                __hip_atomic_store(&h_u[j0 + tid], __float_as_uint(hv),
                    __ATOMIC_RELAXED, __HIP_MEMORY_SCOPE_AGENT);
            }
        }
        gsync(ctrl, e0 + 1);

        // ---- phase C: reload h; logits (blocks<128) || next Wd (>=128) ----
        {
#pragma unroll
            for (int k = 0; k < 4; k++)
                h_s[tid + 512 * k] = __uint_as_float(__hip_atomic_load(
                    &h_u[tid + 512 * k], __ATOMIC_RELAXED,
                    __HIP_MEMORY_SCOPE_AGENT));
            __syncthreads();
            if (blockIdx.x < OUT_) {
                float4 w4 =
                    ((const float4*)(h2oW + (size_t)blockIdx.x * H))[tid];
                float4 h4 = ((const float4*)h_s)[tid];
                float p = w4.x * h4.x + w4.y * h4.y + w4.z * h4.z + w4.w * h4.w;
#pragma unroll
                for (int off = 32; off; off >>= 1) p += __shfl_xor(p, off, 64);
                if (ln == 0) red8[wv] = p;
                __syncthreads();
                if (tid == 0) {
                    float ss = red8[0] + red8[1] + red8[2] + red8[3] +
                               red8[4] + red8[5] + red8[6] + red8[7];
                    __hip_atomic_store(&lg_u[blockIdx.x],
                        __float_as_uint(ss + h2ob[blockIdx.x]),
                        __ATOMIC_RELAXED, __HIP_MEMORY_SCOPE_AGENT);
                }
            } else {
                int r0 = (blockIdx.x - OUT_) * 16 + wv * 2;
#pragma unroll
                for (int rr = 0; rr < 2; rr++) {
                    int row = r0 + rr;
                    const float4* wr = (const float4*)(WW + (size_t)row * H);
                    float p = 0.f;
#pragma unroll
                    for (int m2 = 0; m2 < 8; m2++) {
                        float4 w4 = wr[ln + (m2 << 6)];
                        float4 h4 = ((const float4*)h_s)[ln + (m2 << 6)];
                        p += w4.x * h4.x + w4.y * h4.y + w4.z * h4.z +
                             w4.w * h4.w;
                    }
#pragma unroll
                    for (int off = 32; off; off >>= 1)
                        p += __shfl_xor(p, off, 64);
                    if (ln == 0)
                        __hip_atomic_store(&wd_u[row],
                            __float_as_uint(p + Wb[row]),
                            __ATOMIC_RELAXED, __HIP_MEMORY_SCOPE_AGENT);
                }
            }
        }
        gsync(ctrl, e0 + 2);

        // ---- block-local argmax + log-softmax (block 0 writes outs) ----
        {
            if (tid < OUT_)
                lg_s[tid] = __uint_as_float(__hip_atomic_load(&lg_u[tid],
                    __ATOMIC_RELAXED, __HIP_MEMORY_SCOPE_AGENT));
            __syncthreads();
            if (tid == 0) {
                float mx = lg_s[0]; int amx = 0;
                for (int i = 1; i < OUT_; i++)
                    if (lg_s[i] > mx) { mx = lg_s[i]; amx = i; }
                float ss = 0.f;
                for (int i = 0; i < OUT_; i++) ss += expf(lg_s[i] - mx);
                m_sh = mx; s_sh = logf(ss); am_sh = amx;
            }
            __syncthreads();
            am = am_sh;
            if (blockIdx.x == 0 && tid < OUT_)
                outs[(size_t)s * OUT_ + tid] = (lg_s[tid] - m_sh) - s_sh;
            __syncthreads();
        }
    }
}

extern "C" void kernel_launch(void* const* d_in, const int* in_sizes, int n_in,
                              void* d_out, int out_size, void* d_ws, size_t ws_size,
                              hipStream_t stream)
{
    const float* x     = (const float*)d_in[0];
    const float* eWih  = (const float*)d_in[1];
    const float* eWhh  = (const float*)d_in[2];
    const float* ebih  = (const float*)d_in[3];
    const float* ebhh  = (const float*)d_in[4];
    const float* dWih  = (const float*)d_in[5];
    const float* dWhh  = (const float*)d_in[6];
    const float* dbih  = (const float*)d_in[7];
    const float* dbhh  = (const float*)d_in[8];
    const float* h2oW  = (const float*)d_in[9];
    const float* h2ob  = (const float*)d_in[10];
    const float* UW    = (const float*)d_in[11];
    const float* Ub    = (const float*)d_in[12];
    const float* WW    = (const float*)d_in[13];
    const float* Wb    = (const float*)d_in[14];
    const float* attnW = (const float*)d_in[15];
    const float* attnb = (const float*)d_in[16];
    const float* o2hW  = (const float*)d_in[17];
    const float* o2hb  = (const float*)d_in[18];

    float* ws      = (float*)d_ws;
    unsigned* ctrl = (unsigned*)ws;                    // [0..255] enc, [256..511] dec
    float* zrow    = ws + 512;                         // 2048 zeros (h_0)
    float* enc_out = zrow + H;                         // 512*2048
    float* gi_all  = enc_out + (size_t)T_ * H;         // 512*6144
    float* U       = gi_all + (size_t)T_ * 3 * H;      // 512*2048
    float* E       = U + (size_t)T_ * H;               // 128*2048
    float* G       = E + (size_t)OUT_ * H;             // 6144*128
    float* p0      = G + (size_t)3 * H * OUT_;         // 6144
    float* M_ws    = p0 + 3 * H;                       // 6144*512
    float* Wd      = M_ws + (size_t)3 * H * T_;        // 2048
    float* scores  = Wd + H;                           // 512
    float* logits  = scores + T_;                      // 128
    float* hd      = logits + OUT_;                    // 2048

    float* outs  = (float*)d_out;                      // 64*128
    float* attns = outs + STEPS * OUT_;                // 64*512

    // zero barrier flags + h0 row (d_ws is poisoned before every call)
    hipMemsetAsync(d_ws, 0, (512 + H) * sizeof(float), stream);

    // ---- encoder input gemm ----
    gemm_abt<<<dim3(3 * H / BN, T_ / BM), 256, 0, stream>>>(
        x, eWih, ebih, gi_all, T_, 3 * H, IN_, IN_);

    // ---- decoder precompute (independent of encoder) ----
    ebuild_kernel<<<dim3(H / 256, OUT_), 256, 0, stream>>>(o2hW, o2hb, E);
    gemm_abt<<<dim3(OUT_ / BN, 3 * H / BM), 256, 0, stream>>>(
        dWih, E, nullptr, G, 3 * H, OUT_, H, 2 * H);
    p0_kernel<<<3 * H / 8, 512, 0, stream>>>(dWih, o2hb, p0);

    // ---- encoder recurrence (also produces M = dWih_right @ enc_out^T) ----
    enc_persistent<<<256, 512, 0, stream>>>(eWhh, ebhh, gi_all, dWih,
                                            enc_out, M_ws, ctrl);

    gemm_abt<<<dim3(H / BN, T_ / BM), 256, 0, stream>>>(
        enc_out, UW, Ub, U, T_, H, H, H);

    // ---- decoder: single persistent kernel ----
    dec_persistent<<<256, 512, 0, stream>>>(
        dWhh, dbih, dbhh, h2oW, h2ob, WW, Wb, attnW, attnb,
        G, p0, U, enc_out, M_ws,
        Wd, scores, logits, hd,
        outs, attns, ctrl + 256);
}

// Round 4
// 3194.248 us; speedup vs baseline: 2.6481x; 1.6933x over previous
//
#include <hip/hip_runtime.h>
#include <math.h>

// Sizes fixed by setup_inputs(): H=2048, IN=128, OUT=128, T=512, STEPS=64
#define H    2048
#define IN_  128
#define OUT_ 128
#define T_   512
#define STEPS 64

typedef unsigned long long u64;

// ---------------------------------------------------------------------------
// Self-stamped dataflow primitives. A {epoch,value} pair in ONE 64-bit relaxed
// agent-scope atomic (single-copy atomic at the IC coherence point): validity
// travels WITH the data. No release ack, no flag store, no separate data load,
// no grid barrier. Pub arrays are written once per address (no ABA); zeroed
// once at launch (tags start at 1).
// ---------------------------------------------------------------------------
__device__ __forceinline__ u64 ld_pair(const u64* p) {
    return __hip_atomic_load(p, __ATOMIC_RELAXED, __HIP_MEMORY_SCOPE_AGENT);
}
__device__ __forceinline__ void st_pair(u64* p, unsigned tag, float x) {
    u64 v = ((u64)tag << 32) | (u64)__float_as_uint(x);
    __hip_atomic_store(p, v, __ATOMIC_RELAXED, __HIP_MEMORY_SCOPE_AGENT);
}
__device__ __forceinline__ float poll1(const u64* p, unsigned tag) {
    u64 v = ld_pair(p);
    while ((unsigned)(v >> 32) != tag) {
        __builtin_amdgcn_s_sleep(1);
        v = ld_pair(p);
    }
    return __uint_as_float((unsigned)v);
}
// 2048 pairs -> LDS float buffer; thread tid handles {tid, tid+512, ...}.
__device__ __forceinline__ void poll4(const u64* base, unsigned tag,
                                      float* dst, int tid) {
    u64 v[4];
#pragma unroll
    for (int k = 0; k < 4; k++) v[k] = ld_pair(base + tid + 512 * k);
    for (;;) {
        bool all = true;
#pragma unroll
        for (int k = 0; k < 4; k++) all &= ((unsigned)(v[k] >> 32) == tag);
        if (all) break;
        __builtin_amdgcn_s_sleep(1);
#pragma unroll
        for (int k = 0; k < 4; k++)
            if ((unsigned)(v[k] >> 32) != tag)
                v[k] = ld_pair(base + tid + 512 * k);
    }
#pragma unroll
    for (int k = 0; k < 4; k++) dst[tid + 512 * k] = __uint_as_float((unsigned)v[k]);
}

// ---------------------------------------------------------------------------
// Generic tiled GEMM: C[M,N] = A[M,K(lda)] @ B[N,K]^T + bias[N]  (row-major)
// ---------------------------------------------------------------------------
#define BM 64
#define BN 64
#define BK 16
__global__ __launch_bounds__(256) void gemm_abt(
    const float* __restrict__ A, const float* __restrict__ B,
    const float* __restrict__ bias, float* __restrict__ C,
    int M, int N, int K, int lda)
{
    __shared__ float As[BM][BK + 1];
    __shared__ float Bs[BN][BK + 1];
    int tid = threadIdx.x;
    int m0 = blockIdx.y * BM, n0 = blockIdx.x * BN;
    int ty = tid / 16, tx = tid % 16;
    float acc[4][4] = {};
    int r = tid >> 2, q = tid & 3;
    for (int k0 = 0; k0 < K; k0 += BK) {
        float4 a4 = *(const float4*)(A + (size_t)(m0 + r) * lda + k0 + q * 4);
        As[r][q * 4 + 0] = a4.x; As[r][q * 4 + 1] = a4.y;
        As[r][q * 4 + 2] = a4.z; As[r][q * 4 + 3] = a4.w;
        float4 b4 = *(const float4*)(B + (size_t)(n0 + r) * K + k0 + q * 4);
        Bs[r][q * 4 + 0] = b4.x; Bs[r][q * 4 + 1] = b4.y;
        Bs[r][q * 4 + 2] = b4.z; Bs[r][q * 4 + 3] = b4.w;
        __syncthreads();
#pragma unroll
        for (int kk = 0; kk < BK; kk++) {
            float a[4], b[4];
#pragma unroll
            for (int i = 0; i < 4; i++) a[i] = As[ty * 4 + i][kk];
#pragma unroll
            for (int j = 0; j < 4; j++) b[j] = Bs[tx * 4 + j][kk];
#pragma unroll
            for (int i = 0; i < 4; i++)
#pragma unroll
                for (int j = 0; j < 4; j++) acc[i][j] += a[i] * b[j];
        }
        __syncthreads();
    }
#pragma unroll
    for (int j = 0; j < 4; j++) {
        float bv = bias ? bias[n0 + tx * 4 + j] : 0.f;
#pragma unroll
        for (int i = 0; i < 4; i++)
            C[(size_t)(m0 + ty * 4 + i) * N + n0 + tx * 4 + j] = acc[i][j] + bv;
    }
}

// E[c][j] = o2hW[j][c] + o2hb[j]   (128 x 2048)
__global__ __launch_bounds__(256) void ebuild_kernel(
    const float* __restrict__ o2hW, const float* __restrict__ o2hb,
    float* __restrict__ E)
{
    int j = blockIdx.x * 256 + threadIdx.x;
    int c = blockIdx.y;
    E[(size_t)c * H + j] = o2hW[(size_t)j * OUT_ + c] + o2hb[j];
}

// p0[row] = Wih[row, 0:2048] . o2hb     (row stride 4096) — emb for am = -1
__global__ __launch_bounds__(512) void p0_kernel(
    const float* __restrict__ Wih, const float* __restrict__ o2hb,
    float* __restrict__ p0)
{
    __shared__ float b_s[H];
    int tid = threadIdx.x;
    ((float4*)b_s)[tid] = ((const float4*)o2hb)[tid];
    __syncthreads();
    int wv = tid >> 6, ln = tid & 63;
    int row = blockIdx.x * 8 + wv;
    const float4* wr = (const float4*)(Wih + (size_t)row * (2 * H));
    float s = 0.f;
#pragma unroll
    for (int m = 0; m < 8; m++) {
        float4 w = wr[ln + (m << 6)];
        float4 b = ((const float4*)b_s)[ln + (m << 6)];
        s += w.x * b.x + w.y * b.y + w.z * b.z + w.w * b.w;
    }
#pragma unroll
    for (int off = 32; off; off >>= 1) s += __shfl_xor(s, off, 64);
    if (ln == 0) p0[row] = s;
}

// ---------------------------------------------------------------------------
// Persistent encoder: 256 blocks x 512 threads. Block b owns units j0=8b..+7
// (24 rows enc_Whh + 24 rows dec_Wih_right register/AGPR-resident).
// Barrier-free: h values published as {epoch,h} pairs; consumers poll the
// pairs directly. h_t also plain-stored into gi_all row t's first 2048 slots
// (dead after this iteration; aliased "enc_out" with lda=3H downstream).
// M[:,t-1] = dWih_r @ h_{t-1} computed in the wait slack.
// ---------------------------------------------------------------------------
__global__ __launch_bounds__(512, 2) void enc_persistent(
    const float* __restrict__ Whh, const float* __restrict__ bhh,
    float* __restrict__ gio, const float* __restrict__ dWih,
    u64* __restrict__ hpub, float* __restrict__ M_ws)
{
    __shared__ float h_s[H];
    __shared__ float red_s[24];
    const int tid = threadIdx.x;
    const int wv = tid >> 6, ln = tid & 63;
    const int j0 = blockIdx.x * 8;

    float4 wreg[3][8];   // enc_Whh rows
    float4 dreg[3][8];   // dec_Wih right-half rows (for M)
    float bias[3];
    int sidx[3], drow[3];
#pragma unroll
    for (int i = 0; i < 3; i++) {
        int ridx = wv * 3 + i;
        int u = ridx & 7, g = ridx >> 3;
        int row = g * H + j0 + u;
        const float4* wr = (const float4*)(Whh + (size_t)row * H);
        const float4* dr = (const float4*)(dWih + (size_t)row * (2 * H) + H);
#pragma unroll
        for (int m = 0; m < 8; m++) {
            wreg[i][m] = wr[ln + (m << 6)];
            dreg[i][m] = dr[ln + (m << 6)];
        }
        bias[i] = bhh[row];
        sidx[i] = g * 8 + u;
        drow[i] = row;
    }

    for (int t = 0; t < T_; t++) {
        float ir = 0.f, iz = 0.f, inn = 0.f;
        if (tid < 8) {  // issue before the wait (independent of h)
            const float* gi = gio + (size_t)t * 3 * H;
            ir  = gi[j0 + tid];
            iz  = gi[H + j0 + tid];
            inn = gi[2 * H + j0 + tid];
        }
        if (t == 0) {
#pragma unroll
            for (int k = 0; k < 4; k++) h_s[tid + 512 * k] = 0.f;
        } else {
            poll4(hpub + (size_t)(t - 1) * H, (unsigned)t, h_s, tid);
        }
        __syncthreads();

        float s0 = 0.f, s1 = 0.f, s2 = 0.f;
#pragma unroll
        for (int m = 0; m < 8; m++) {
            float4 h4 = ((const float4*)h_s)[ln + (m << 6)];
            s0 += wreg[0][m].x * h4.x + wreg[0][m].y * h4.y +
                  wreg[0][m].z * h4.z + wreg[0][m].w * h4.w;
            s1 += wreg[1][m].x * h4.x + wreg[1][m].y * h4.y +
                  wreg[1][m].z * h4.z + wreg[1][m].w * h4.w;
            s2 += wreg[2][m].x * h4.x + wreg[2][m].y * h4.y +
                  wreg[2][m].z * h4.z + wreg[2][m].w * h4.w;
        }
#pragma unroll
        for (int off = 32; off; off >>= 1) {
            s0 += __shfl_xor(s0, off, 64);
            s1 += __shfl_xor(s1, off, 64);
            s2 += __shfl_xor(s2, off, 64);
        }
        if (ln == 0) {
            red_s[sidx[0]] = s0 + bias[0];
            red_s[sidx[1]] = s1 + bias[1];
            red_s[sidx[2]] = s2 + bias[2];
        }
        __syncthreads();

        if (tid < 8) {
            float hr = red_s[tid], hz = red_s[8 + tid], hn = red_s[16 + tid];
            float rg = 1.f / (1.f + expf(-(ir + hr)));
            float zg = 1.f / (1.f + expf(-(iz + hz)));
            float ng = tanhf(inn + rg * hn);
            float hv = (1.f - zg) * ng + zg * h_s[j0 + tid];
            gio[(size_t)t * 3 * H + j0 + tid] = hv;        // aliased enc_out
            st_pair(&hpub[(size_t)t * H + j0 + tid], (unsigned)(t + 1), hv);
        }

        // slack work: M[:,t-1] = dWih_r @ h_{t-1}
        if (t > 0) {
            float m0 = 0.f, m1 = 0.f, m2 = 0.f;
#pragma unroll
            for (int m = 0; m < 8; m++) {
                float4 h4 = ((const float4*)h_s)[ln + (m << 6)];
                m0 += dreg[0][m].x * h4.x + dreg[0][m].y * h4.y +
                      dreg[0][m].z * h4.z + dreg[0][m].w * h4.w;
                m1 += dreg[1][m].x * h4.x + dreg[1][m].y * h4.y +
                      dreg[1][m].z * h4.z + dreg[1][m].w * h4.w;
                m2 += dreg[2][m].x * h4.x + dreg[2][m].y * h4.y +
                      dreg[2][m].z * h4.z + dreg[2][m].w * h4.w;
            }
#pragma unroll
            for (int off = 32; off; off >>= 1) {
                m0 += __shfl_xor(m0, off, 64);
                m1 += __shfl_xor(m1, off, 64);
                m2 += __shfl_xor(m2, off, 64);
            }
            if (ln == 0) {
                M_ws[(size_t)drow[0] * T_ + (t - 1)] = m0;
                M_ws[(size_t)drow[1] * T_ + (t - 1)] = m1;
                M_ws[(size_t)drow[2] * T_ + (t - 1)] = m2;
            }
        }
        __syncthreads();  // protect h_s before next iteration overwrites
    }

    // epilogue: M[:,T-1] from h_T
    poll4(hpub + (size_t)(T_ - 1) * H, (unsigned)T_, h_s, tid);
    __syncthreads();
    {
        float m0 = 0.f, m1 = 0.f, m2 = 0.f;
#pragma unroll
        for (int m = 0; m < 8; m++) {
            float4 h4 = ((const float4*)h_s)[ln + (m << 6)];
            m0 += dreg[0][m].x * h4.x + dreg[0][m].y * h4.y +
                  dreg[0][m].z * h4.z + dreg[0][m].w * h4.w;
            m1 += dreg[1][m].x * h4.x + dreg[1][m].y * h4.y +
                  dreg[1][m].z * h4.z + dreg[1][m].w * h4.w;
            m2 += dreg[2][m].x * h4.x + dreg[2][m].y * h4.y +
                  dreg[2][m].z * h4.z + dreg[2][m].w * h4.w;
        }
#pragma unroll
        for (int off = 32; off; off >>= 1) {
            m0 += __shfl_xor(m0, off, 64);
            m1 += __shfl_xor(m1, off, 64);
            m2 += __shfl_xor(m2, off, 64);
        }
        if (ln == 0) {
            M_ws[(size_t)drow[0] * T_ + (T_ - 1)] = m0;
            M_ws[(size_t)drow[1] * T_ + (T_ - 1)] = m1;
            M_ws[(size_t)drow[2] * T_ + (T_ - 1)] = m2;
        }
    }
}

// ---------------------------------------------------------------------------
// Persistent decoder: 256 blocks x 512 threads, all 64 steps, ZERO barriers.
// Dataflow waits only: A(Wd) -> scores ; B(scores) -> h ; C(h) -> logits/Wd'.
// Whh in registers, M-slab in LDS; gi-left from precomputed G[:,am]/p0.
// argmax/log-softmax of step s-1 parallelized inside phase A of step s.
// ---------------------------------------------------------------------------
__global__ __launch_bounds__(512, 1) void dec_persistent(
    const float* __restrict__ Whh,
    const float* __restrict__ bih, const float* __restrict__ bhh,
    const float* __restrict__ h2oW, const float* __restrict__ h2ob,
    const float* __restrict__ WW, const float* __restrict__ Wb,
    const float* __restrict__ attnW, const float* __restrict__ attnb,
    const float* __restrict__ G, const float* __restrict__ p0,
    const float* __restrict__ U, const float* __restrict__ h0,
    const float* __restrict__ M_ws,
    u64* __restrict__ wdpub, u64* __restrict__ scpub,
    u64* __restrict__ hpubd, u64* __restrict__ lgpub,
    float* __restrict__ outs, float* __restrict__ attns)
{
    __shared__ __align__(16) float h_s[H];
    __shared__ __align__(16) float wd_s[H];
    __shared__ __align__(16) float sc_s[T_];
    __shared__ __align__(16) float M_s[24][T_];   // 48 KB
    __shared__ float lg_s[OUT_];
    __shared__ float red8[8];
    __shared__ int ired[2];
    __shared__ float red_gi[24], red_gh[24];
    __shared__ float m_sh, s_sh;
    __shared__ int am_sh;

    const int tid = threadIdx.x;
    const int wv = tid >> 6, ln = tid & 63;
    const int j0 = blockIdx.x * 8;

    // ---- one-time: dec_Whh rows -> registers; M rows -> LDS ----
    float4 whreg[3][8];
    float bih_r[3], bhh_r[3];
    int sidx[3], rowr[3];
#pragma unroll
    for (int i = 0; i < 3; i++) {
        int ridx = wv * 3 + i;
        int u = ridx & 7, g = ridx >> 3;
        int row = g * H + j0 + u;
        const float4* wr = (const float4*)(Whh + (size_t)row * H);
#pragma unroll
        for (int m = 0; m < 8; m++) whreg[i][m] = wr[ln + (m << 6)];
        bih_r[i] = bih[row];
        bhh_r[i] = bhh[row];
        sidx[i] = g * 8 + u;
        rowr[i] = row;
#pragma unroll
        for (int k = 0; k < 8; k++)
            M_s[ridx][ln + (k << 6)] = M_ws[(size_t)row * T_ + ln + (k << 6)];
    }

    ((float4*)h_s)[tid] = ((const float4*)h0)[tid];   // h^0 = enc h_T
    __syncthreads();

    // ---- prologue: Wd^0 (1 row per wave) ----
    {
        const float4* wr = (const float4*)(WW + (size_t)(j0 + wv) * H);
        float p = 0.f;
#pragma unroll
        for (int m = 0; m < 8; m++) {
            float4 w4 = wr[ln + (m << 6)];
            float4 h4 = ((const float4*)h_s)[ln + (m << 6)];
            p += w4.x * h4.x + w4.y * h4.y + w4.z * h4.z + w4.w * h4.w;
        }
#pragma unroll
        for (int off = 32; off; off >>= 1) p += __shfl_xor(p, off, 64);
        if (ln == 0) st_pair(&wdpub[j0 + wv], 1u, p + Wb[j0 + wv]);
    }

    int am = -1;
    for (int s = 0; s < STEPS; s++) {
        const unsigned tg = (unsigned)(s + 1);

        // ---- phase A: scores (+ argmax/log-softmax of step s-1) ----
        poll4(wdpub + (size_t)s * H, tg, wd_s, tid);
        __syncthreads();
        {
            int t2 = 2 * blockIdx.x + (tid >> 8);
            int r = tid & 255;
            const float* Ut = U + (size_t)t2 * H;
            float p = 0.f;
#pragma unroll
            for (int k = 0; k < 8; k++) {
                int j = r + 256 * k;
                p += tanhf(Ut[j] + wd_s[j]) * attnW[j];
            }
#pragma unroll
            for (int off = 32; off; off >>= 1) p += __shfl_xor(p, off, 64);
            if (ln == 0) red8[wv] = p;
        }
        __syncthreads();
        if (tid == 0)
            st_pair(&scpub[(size_t)s * T_ + 2 * blockIdx.x], tg,
                    red8[0] + red8[1] + red8[2] + red8[3] + attnb[0]);
        if (tid == 256)
            st_pair(&scpub[(size_t)s * T_ + 2 * blockIdx.x + 1], tg,
                    red8[4] + red8[5] + red8[6] + red8[7] + attnb[0]);
        __syncthreads();
        if (s > 0) {
            if (tid < 128) {
                float lv = poll1(&lgpub[(size_t)(s - 1) * OUT_ + tid],
                                 (unsigned)s);
                lg_s[tid] = lv;
                float bv = lv; int bi = tid;
#pragma unroll
                for (int off = 32; off; off >>= 1) {
                    float ov = __shfl_xor(bv, off, 64);
                    int oi = __shfl_xor(bi, off, 64);
                    if (ov > bv || (ov == bv && oi < bi)) { bv = ov; bi = oi; }
                }
                if (ln == 0) { red8[wv] = bv; ired[wv] = bi; }
            }
            __syncthreads();
            if (tid == 0) {
                float ma = red8[0]; int ia = ired[0];
                if (red8[1] > ma || (red8[1] == ma && ired[1] < ia)) {
                    ma = red8[1]; ia = ired[1];
                }
                m_sh = ma; am_sh = ia;
            }
            __syncthreads();
            if (tid < 128) {
                float e = expf(lg_s[tid] - m_sh);
#pragma unroll
                for (int off = 32; off; off >>= 1) e += __shfl_xor(e, off, 64);
                if (ln == 0) red8[2 + wv] = e;
            }
            __syncthreads();
            if (tid == 0) s_sh = logf(red8[2] + red8[3]);
            __syncthreads();
            am = am_sh;
            if (blockIdx.x == 0 && tid < 128)
                outs[(size_t)(s - 1) * OUT_ + tid] = (lg_s[tid] - m_sh) - s_sh;
        }

        // ---- phase B: gh precompute, scores wait, softmax, GRU -> h ----
        float ghp[3];
#pragma unroll
        for (int i = 0; i < 3; i++) {
            float g = 0.f;
#pragma unroll
            for (int m2 = 0; m2 < 8; m2++) {
                float4 h4 = ((const float4*)h_s)[ln + (m2 << 6)];
                float4 w4 = whreg[i][m2];
                g += w4.x * h4.x + w4.y * h4.y + w4.z * h4.z + w4.w * h4.w;
            }
            ghp[i] = g;
        }
        float scv = poll1(&scpub[(size_t)s * T_ + tid], tg);
        float mx = scv;
#pragma unroll
        for (int off = 32; off; off >>= 1)
            mx = fmaxf(mx, __shfl_xor(mx, off, 64));
        if (ln == 0) red8[wv] = mx;
        __syncthreads();
        if (tid == 0) {
            float mm = red8[0];
            for (int i = 1; i < 8; i++) mm = fmaxf(mm, red8[i]);
            m_sh = mm;
        }
        __syncthreads();
        float ev = expf(scv - m_sh);
        float pp = ev;
#pragma unroll
        for (int off = 32; off; off >>= 1) pp += __shfl_xor(pp, off, 64);
        __syncthreads();
        if (ln == 0) red8[wv] = pp;
        __syncthreads();
        if (tid == 0) {
            float ss = 0.f;
            for (int i = 0; i < 8; i++) ss += red8[i];
            s_sh = ss;
        }
        __syncthreads();
        float aw = ev / s_sh;
        sc_s[tid] = aw;
        if (blockIdx.x == 0) attns[(size_t)s * T_ + tid] = aw;
        __syncthreads();
#pragma unroll
        for (int i = 0; i < 3; i++) {
            int row = rowr[i];
            float gil = (am >= 0) ? G[(size_t)row * OUT_ + am] : p0[row];
            const float* Mr = &M_s[wv * 3 + i][0];
            float gi = 0.f;
#pragma unroll
            for (int k = 0; k < 8; k++)
                gi += Mr[ln + (k << 6)] * sc_s[ln + (k << 6)];
            float gh = ghp[i];
#pragma unroll
            for (int off = 32; off; off >>= 1) {
                gi += __shfl_xor(gi, off, 64);
                gh += __shfl_xor(gh, off, 64);
            }
            if (ln == 0) {
                red_gi[sidx[i]] = gi + gil + bih_r[i];
                red_gh[sidx[i]] = gh + bhh_r[i];
            }
        }
        __syncthreads();
        if (tid < 8) {
            float ir = red_gi[tid], iz = red_gi[8 + tid],
                  inn = red_gi[16 + tid];
            float hr = red_gh[tid], hz = red_gh[8 + tid],
                  hn = red_gh[16 + tid];
            float rg = 1.f / (1.f + expf(-(ir + hr)));
            float zg = 1.f / (1.f + expf(-(iz + hz)));
            float ng = tanhf(inn + rg * hn);
            float hv = (1.f - zg) * ng + zg * h_s[j0 + tid];
            st_pair(&hpubd[(size_t)s * H + j0 + tid], tg, hv);
        }
        __syncthreads();  // protect h_s before phase C overwrites

        // ---- phase C: h wait; logits (blocks<128) || Wd^{s+1} (>=128) ----
        poll4(hpubd + (size_t)s * H, tg, h_s, tid);
        __syncthreads();
        if (blockIdx.x < OUT_) {
            float4 w4 = ((const float4*)(h2oW + (size_t)blockIdx.x * H))[tid];
            float4 h4 = ((const float4*)h_s)[tid];
            float p = w4.x * h4.x + w4.y * h4.y + w4.z * h4.z + w4.w * h4.w;
#pragma unroll
            for (int off = 32; off; off >>= 1) p += __shfl_xor(p, off, 64);
            if (ln == 0) red8[wv] = p;
            __syncthreads();
            if (tid == 0)
                st_pair(&lgpub[(size_t)s * OUT_ + blockIdx.x], tg,
                        red8[0] + red8[1] + red8[2] + red8[3] + red8[4] +
                        red8[5] + red8[6] + red8[7] + h2ob[blockIdx.x]);
        } else {
            int r0 = (blockIdx.x - OUT_) * 16 + wv * 2;
#pragma unroll
            for (int rr = 0; rr < 2; rr++) {
                int row = r0 + rr;
                const float4* wr = (const float4*)(WW + (size_t)row * H);
                float p = 0.f;
#pragma unroll
                for (int m2 = 0; m2 < 8; m2++) {
                    float4 w4 = wr[ln + (m2 << 6)];
                    float4 h4 = ((const float4*)h_s)[ln + (m2 << 6)];
                    p += w4.x * h4.x + w4.y * h4.y + w4.z * h4.z + w4.w * h4.w;
                }
#pragma unroll
                for (int off = 32; off; off >>= 1) p += __shfl_xor(p, off, 64);
                if (ln == 0)
                    st_pair(&wdpub[(size_t)(s + 1) * H + row], tg + 1,
                            p + Wb[row]);
            }
        }
        __syncthreads();
    }

    // ---- epilogue: outs[63] (block 0 only) ----
    if (blockIdx.x == 0) {
        if (tid < 128) {
            float lv = poll1(&lgpub[(size_t)(STEPS - 1) * OUT_ + tid],
                             (unsigned)STEPS);
            lg_s[tid] = lv;
            float bv = lv;
#pragma unroll
            for (int off = 32; off; off >>= 1)
                bv = fmaxf(bv, __shfl_xor(bv, off, 64));
            if (ln == 0) red8[wv] = bv;
        }
        __syncthreads();
        if (tid == 0) m_sh = fmaxf(red8[0], red8[1]);
        __syncthreads();
        if (tid < 128) {
            float e = expf(lg_s[tid] - m_sh);
#pragma unroll
            for (int off = 32; off; off >>= 1) e += __shfl_xor(e, off, 64);
            if (ln == 0) red8[2 + wv] = e;
        }
        __syncthreads();
        if (tid == 0) s_sh = logf(red8[2] + red8[3]);
        __syncthreads();
        if (tid < 128)
            outs[(size_t)(STEPS - 1) * OUT_ + tid] = (lg_s[tid] - m_sh) - s_sh;
    }
}

extern "C" void kernel_launch(void* const* d_in, const int* in_sizes, int n_in,
                              void* d_out, int out_size, void* d_ws, size_t ws_size,
                              hipStream_t stream)
{
    const float* x     = (const float*)d_in[0];
    const float* eWih  = (const float*)d_in[1];
    const float* eWhh  = (const float*)d_in[2];
    const float* ebih  = (const float*)d_in[3];
    const float* ebhh  = (const float*)d_in[4];
    const float* dWih  = (const float*)d_in[5];
    const float* dWhh  = (const float*)d_in[6];
    const float* dbih  = (const float*)d_in[7];
    const float* dbhh  = (const float*)d_in[8];
    const float* h2oW  = (const float*)d_in[9];
    const float* h2ob  = (const float*)d_in[10];
    const float* UW    = (const float*)d_in[11];
    const float* Ub    = (const float*)d_in[12];
    const float* WW    = (const float*)d_in[13];
    const float* Wb    = (const float*)d_in[14];
    const float* attnW = (const float*)d_in[15];
    const float* attnb = (const float*)d_in[16];
    const float* o2hW  = (const float*)d_in[17];
    const float* o2hb  = (const float*)d_in[18];

    // ---- workspace layout (u64 pub arrays first; zeroed below) ----
    u64* hpub   = (u64*)d_ws;                          // 512*2048
    u64* wdpub  = hpub + (size_t)T_ * H;               // 65*2048
    u64* scpub  = wdpub + (size_t)(STEPS + 1) * H;     // 64*512
    u64* hpubd  = scpub + (size_t)STEPS * T_;          // 64*2048
    u64* lgpub  = hpubd + (size_t)STEPS * H;           // 64*128
    float* fbase = (float*)(lgpub + (size_t)STEPS * OUT_);
    float* gi_all = fbase;                             // 512*6144 (rows' first
                                                       //  2048 become enc h_t)
    float* U      = gi_all + (size_t)T_ * 3 * H;       // 512*2048
    float* E      = U + (size_t)T_ * H;                // 128*2048
    float* G      = E + (size_t)OUT_ * H;              // 6144*128
    float* p0     = G + (size_t)3 * H * OUT_;          // 6144
    float* M_ws   = p0 + 3 * H;                        // 6144*512

    float* outs  = (float*)d_out;                      // 64*128
    float* attns = outs + STEPS * OUT_;                // 64*512

    // zero all epoch-pair regions (tags are >=1; one bulk memset, ~2 us)
    size_t pub_bytes = ((size_t)T_ * H + (size_t)(STEPS + 1) * H +
                        (size_t)STEPS * T_ + (size_t)STEPS * H +
                        (size_t)STEPS * OUT_) * sizeof(u64);
    hipMemsetAsync(d_ws, 0, pub_bytes, stream);

    // ---- encoder input gemm ----
    gemm_abt<<<dim3(3 * H / BN, T_ / BM), 256, 0, stream>>>(
        x, eWih, ebih, gi_all, T_, 3 * H, IN_, IN_);

    // ---- decoder precompute (independent of encoder) ----
    ebuild_kernel<<<dim3(H / 256, OUT_), 256, 0, stream>>>(o2hW, o2hb, E);
    gemm_abt<<<dim3(OUT_ / BN, 3 * H / BM), 256, 0, stream>>>(
        dWih, E, nullptr, G, 3 * H, OUT_, H, 2 * H);
    p0_kernel<<<3 * H / 8, 512, 0, stream>>>(dWih, o2hb, p0);

    // ---- encoder recurrence (also produces M = dWih_right @ enc_out^T) ----
    enc_persistent<<<256, 512, 0, stream>>>(eWhh, ebhh, gi_all, dWih,
                                            hpub, M_ws);

    // U = enc_out @ UW^T + Ub  (enc_out aliased in gi_all, lda = 3H)
    gemm_abt<<<dim3(H / BN, T_ / BM), 256, 0, stream>>>(
        gi_all, UW, Ub, U, T_, H, H, 3 * H);

    // ---- decoder: single persistent kernel, dataflow-synchronized ----
    const float* h0 = gi_all + (size_t)(T_ - 1) * 3 * H;
    dec_persistent<<<256, 512, 0, stream>>>(
        dWhh, dbih, dbhh, h2oW, h2ob, WW, Wb, attnW, attnb,
        G, p0, U, h0, M_ws,
        wdpub, scpub, hpubd, lgpub,
        outs, attns);
}